// Round 13
// baseline (605.087 us; speedup 1.0000x reference)
//
#include <hip/hip_runtime.h>

// Problem constants
#define NNODES 65536
#define NEDGES 524288

typedef short bf16x8 __attribute__((ext_vector_type(8)));
typedef float f32x4 __attribute__((ext_vector_type(4)));

// Packed-weight fragment offsets (in bf16 elements) within the weight region.
// Fragment layout per matrix (K x NC): [n_tile][k_tile][lane][8], 512 bf16 per fragment.
#define OF_MW1 0        // 320x256: KT=10, NT=16 -> 81920
#define OF_MW2 81920    // 256x256: KT=8,  NT=16 -> 65536
#define OF_MW3 147456   // 256x128: KT=8,  NT=8  -> 32768
#define OF_UW1 180224   // 384x256: KT=12, NT=16 -> 98304
#define OF_UW2 278528   // 256x256: KT=8,  NT=16 -> 65536
#define OF_UW3 344064   // 256x128: KT=8,  NT=8  -> 32768
#define WF_BYTES (376832 * 2)

// Big-workspace layout (CSR path, tier 1)
#define WS_MSGS_BYTES ((size_t)NEDGES * 128 * 2)          // 134217728 (bf16)
#define WS_NSB_OFF    WS_MSGS_BYTES
#define WS_NSB_BYTES  ((size_t)NNODES * 128 * 2)          // 16777216 (bf16 node table)
#define WS_EIDX_OFF   (WS_NSB_OFF + WS_NSB_BYTES)
#define WS_EIDX_BYTES ((size_t)NNODES * 64 * 4)           // 16777216
#define WS_CNT_OFF    (WS_EIDX_OFF + WS_EIDX_BYTES)
#define WS_CNT_BYTES  ((size_t)NNODES * 4)                // 262144
#define WS_WF_OFF     (WS_CNT_OFF + WS_CNT_BYTES)
#define WS_NEED       (WS_WF_OFF + WF_BYTES)
// Tier 2 adds a bf16 edge table at the end.
#define WS_EB_OFF     WS_NEED
#define WS_EB_BYTES   ((size_t)NEDGES * 64 * 2)           // 67108864
#define WS_NEED2      (WS_EB_OFF + WS_EB_BYTES)

// Fallback layout (atomic path)
#define WS_SUMMED_BYTES ((size_t)NNODES * 128 * 4)

__device__ __forceinline__ unsigned short f2bf(float x) {
  unsigned int u = __float_as_uint(x);
  return (unsigned short)((u + 0x7FFFu + ((u >> 16) & 1u)) >> 16);  // RNE
}

__device__ __forceinline__ float bf2f(short s) {
  return __uint_as_float((unsigned int)(unsigned short)s << 16);
}

// v_cvt_pk_bf16_f32 (RNE): result.lo16 = bf16(a), result.hi16 = bf16(b).
__device__ __forceinline__ unsigned int cvtpk(float a, float b) {
  unsigned int r;
  asm("v_cvt_pk_bf16_f32 %0, %1, %2" : "=v"(r) : "v"(a), "v"(b));
  return r;
}

// Pack 8 f32 -> 8 bf16 (one 16B store) via 4 packed converts.
__device__ __forceinline__ void cvt_store8(unsigned short* p, float4 a, float4 b) {
  *reinterpret_cast<uint4*>(p) =
      make_uint4(cvtpk(a.x, a.y), cvtpk(a.z, a.w), cvtpk(b.x, b.y), cvtpk(b.z, b.w));
}

// Tile GEMM from LDS with 1-deep register prefetch of next-kt A and B fragments.
template <int MT, int KT, int NTW>
__device__ __forceinline__ void gemm_tile(const unsigned short* A, const int lda,
                                          const unsigned short* Wf,
                                          f32x4 (&acc)[MT][NTW], const int lane) {
  const int ar = lane & 15;
  const int ak = (lane >> 4) << 3;
  bf16x8 bcur[NTW], acur[MT];
#pragma unroll
  for (int n = 0; n < NTW; ++n)
    bcur[n] = *reinterpret_cast<const bf16x8*>(&Wf[(size_t)(n * KT) * 512 + lane * 8]);
#pragma unroll
  for (int m = 0; m < MT; ++m)
    acur[m] = *reinterpret_cast<const bf16x8*>(&A[(m * 16 + ar) * lda + ak]);
#pragma unroll
  for (int kt = 0; kt < KT; ++kt) {
    bf16x8 bnxt[NTW], anxt[MT];
    if (kt + 1 < KT) {
#pragma unroll
      for (int n = 0; n < NTW; ++n)
        bnxt[n] = *reinterpret_cast<const bf16x8*>(
            &Wf[(size_t)(n * KT + kt + 1) * 512 + lane * 8]);
#pragma unroll
      for (int m = 0; m < MT; ++m)
        anxt[m] = *reinterpret_cast<const bf16x8*>(
            &A[(m * 16 + ar) * lda + (kt + 1) * 32 + ak]);
    }
#pragma unroll
    for (int n = 0; n < NTW; ++n)
#pragma unroll
      for (int m = 0; m < MT; ++m)
        acc[m][n] = __builtin_amdgcn_mfma_f32_16x16x32_bf16(acur[m], bcur[n], acc[m][n], 0, 0, 0);
    if (kt + 1 < KT) {
#pragma unroll
      for (int n = 0; n < NTW; ++n) bcur[n] = bnxt[n];
#pragma unroll
      for (int m = 0; m < MT; ++m) acur[m] = anxt[m];
    }
  }
}

// Convert all six weight matrices into MFMA B-fragment order (bf16).
__global__ void prep_weights(const float* __restrict__ mW1, const float* __restrict__ mW2,
                             const float* __restrict__ mW3, const float* __restrict__ uW1,
                             const float* __restrict__ uW2, const float* __restrict__ uW3,
                             unsigned short* __restrict__ wf) {
  const int f = blockIdx.x;
  const int lane = threadIdx.x;
  const float* W; int NC, KT, fl, base;
  if (f < 160)      { W = mW1; NC = 256; KT = 10; fl = f;       base = OF_MW1; }
  else if (f < 288) { W = mW2; NC = 256; KT = 8;  fl = f - 160; base = OF_MW2; }
  else if (f < 352) { W = mW3; NC = 128; KT = 8;  fl = f - 288; base = OF_MW3; }
  else if (f < 544) { W = uW1; NC = 256; KT = 12; fl = f - 352; base = OF_UW1; }
  else if (f < 672) { W = uW2; NC = 256; KT = 8;  fl = f - 544; base = OF_UW2; }
  else              { W = uW3; NC = 128; KT = 8;  fl = f - 672; base = OF_UW3; }
  const int n_t = fl / KT;
  const int k_t = fl % KT;
  const int col = n_t * 16 + (lane & 15);
  const int krow = k_t * 32 + ((lane >> 4) << 3);
  unsigned short* dst = wf + base + (size_t)fl * 512 + lane * 8;
#pragma unroll
  for (int e = 0; e < 8; ++e) dst[e] = f2bf(W[(size_t)(krow + e) * NC + col]);
}

// Stream-convert node_states (and optionally edges) to bf16 tables. One launch.
__global__ void prep_data(const float* __restrict__ ns, unsigned short* __restrict__ nsb,
                          const float* __restrict__ edg, unsigned short* __restrict__ eb) {
  const int b = blockIdx.x;
  if (b < 4096) {
    const size_t i = ((size_t)b * 256 + threadIdx.x) * 8;
    const float4* s = reinterpret_cast<const float4*>(ns + i);
    cvt_store8(&nsb[i], s[0], s[1]);
  } else if (eb != nullptr) {
    const size_t i = ((size_t)(b - 4096) * 256 + threadIdx.x) * 8;
    const float4* s = reinterpret_cast<const float4*>(edg + i);
    cvt_store8(&eb[i], s[0], s[1]);
  }
}

// Bucket fill: one thread per endpoint entry (2E total).
__global__ void fill_csr(const int* __restrict__ verts, int* __restrict__ cnt,
                         int* __restrict__ eidx) {
  const int k = blockIdx.x * 256 + threadIdx.x;
  const int v = verts[k];
  const int slot = atomicAdd(&cnt[v], 1);
  if (slot < 64) eidx[(size_t)v * 64 + slot] = k >> 1;  // message row = edge id
}

// Message MLP. 64 edges per workgroup, 4 waves in a 2M x 2N grid: wave (mi,ni)
// owns rows mi*32..mi*32+31 and cols ni*128.. (halves A-fragment LDS reads vs 1Mx4N).
// MODE: 0 = atomic fallback (f32 sources), 1 = CSR + f32 edges, 2 = CSR + bf16 edges.
// LDS = 64*328*2 = 41984 B -> 3 blocks/CU.
template <int MODE>
__global__ __launch_bounds__(256, 3) void msg_kernel(
    const float* __restrict__ ns, const unsigned short* __restrict__ nsb,
    const float* __restrict__ edg, const unsigned short* __restrict__ eb,
    const int* __restrict__ verts, const unsigned short* __restrict__ wf,
    const float* __restrict__ mb1, const float* __restrict__ mb2,
    const float* __restrict__ mb3, float* __restrict__ summed,
    unsigned short* __restrict__ msgs) {
  extern __shared__ unsigned short smem[];
  unsigned short* Xs = smem;  // [64][328] bf16; X cols 0..319, then H 0..255

  const int tid = threadIdx.x;
  const int lane = tid & 63;
  const int w = tid >> 6;
  const int mi = w & 1;       // m-half: rows mi*32..mi*32+31
  const int ni = w >> 1;      // n-half: cols ni*128..
  const int e0 = blockIdx.x * 64;

  // Merged staging: [node_i | node_j | edge] -> Xs, ONE barrier.
  {
    const int r = tid >> 4;
    const int c = (tid & 15) * 8;
#pragma unroll
    for (int p = 0; p < 4; ++p) {
      const int row = p * 16 + r;
      const int2 vv = *reinterpret_cast<const int2*>(&verts[(size_t)(e0 + row) * 2]);
      if constexpr (MODE == 0) {
        const float4* s0 = reinterpret_cast<const float4*>(ns + (size_t)vv.x * 128 + c);
        cvt_store8(&Xs[row * 328 + c], s0[0], s0[1]);
        const float4* s1 = reinterpret_cast<const float4*>(ns + (size_t)vv.y * 128 + c);
        cvt_store8(&Xs[row * 328 + 128 + c], s1[0], s1[1]);
      } else {
        *reinterpret_cast<bf16x8*>(&Xs[row * 328 + c]) =
            *reinterpret_cast<const bf16x8*>(&nsb[(size_t)vv.x * 128 + c]);
        *reinterpret_cast<bf16x8*>(&Xs[row * 328 + 128 + c]) =
            *reinterpret_cast<const bf16x8*>(&nsb[(size_t)vv.y * 128 + c]);
      }
    }
#pragma unroll
    for (int i = tid; i < 512; i += 256) {
      const int row = i >> 3;
      const int cc = (i & 7) * 8;
      if constexpr (MODE == 2) {
        *reinterpret_cast<bf16x8*>(&Xs[row * 328 + 256 + cc]) =
            *reinterpret_cast<const bf16x8*>(&eb[(size_t)(e0 + row) * 64 + cc]);
      } else {
        const float4* s2 = reinterpret_cast<const float4*>(edg + (size_t)(e0 + row) * 64 + cc);
        cvt_store8(&Xs[row * 328 + 256 + cc], s2[0], s2[1]);
      }
    }
  }
  __syncthreads();

  const int cw = lane & 15;
  const int rq = (lane >> 4) * 4;
  const unsigned short* Arows = Xs + (size_t)(mi * 32) * 328;

  // Layer 1: 320 -> 256, relu. Wave (mi,ni): rows mi*32+.., cols ni*128+0..127.
  {
    f32x4 acc[2][8];
#pragma unroll
    for (int m = 0; m < 2; ++m)
#pragma unroll
      for (int n = 0; n < 8; ++n)
#pragma unroll
        for (int i = 0; i < 4; ++i) acc[m][n][i] = 0.0f;
    gemm_tile<2, 10, 8>(Arows, 328, wf + OF_MW1 + (size_t)(ni * 8) * 10 * 512, acc, lane);
    __syncthreads();
#pragma unroll
    for (int n = 0; n < 8; ++n) {
      const int col = ni * 128 + n * 16 + cw;
      const float bias = mb1[col];
#pragma unroll
      for (int m = 0; m < 2; ++m)
#pragma unroll
        for (int q = 0; q < 4; ++q) {
          const int row = mi * 32 + m * 16 + rq + q;
          Xs[row * 328 + col] = f2bf(fmaxf(acc[m][n][q] + bias, 0.0f));
        }
    }
  }
  __syncthreads();

  // Layer 2: 256 -> 256, relu, in-place on Xs.
  {
    f32x4 acc[2][8];
#pragma unroll
    for (int m = 0; m < 2; ++m)
#pragma unroll
      for (int n = 0; n < 8; ++n)
#pragma unroll
        for (int i = 0; i < 4; ++i) acc[m][n][i] = 0.0f;
    gemm_tile<2, 8, 8>(Arows, 328, wf + OF_MW2 + (size_t)(ni * 8) * 8 * 512, acc, lane);
    __syncthreads();
#pragma unroll
    for (int n = 0; n < 8; ++n) {
      const int col = ni * 128 + n * 16 + cw;
      const float bias = mb2[col];
#pragma unroll
      for (int m = 0; m < 2; ++m)
#pragma unroll
        for (int q = 0; q < 4; ++q) {
          const int row = mi * 32 + m * 16 + rq + q;
          Xs[row * 328 + col] = f2bf(fmaxf(acc[m][n][q] + bias, 0.0f));
        }
    }
  }
  __syncthreads();

  // Layer 3: 256 -> 128, straight from accumulators to output. Cols ni*64+0..63.
  {
    f32x4 acc[2][4];
#pragma unroll
    for (int m = 0; m < 2; ++m)
#pragma unroll
      for (int n = 0; n < 4; ++n)
#pragma unroll
        for (int i = 0; i < 4; ++i) acc[m][n][i] = 0.0f;
    gemm_tile<2, 8, 4>(Arows, 328, wf + OF_MW3 + (size_t)(ni * 4) * 8 * 512, acc, lane);

    if constexpr (MODE == 0) {
#pragma unroll
      for (int n = 0; n < 4; ++n) {
        const int col = ni * 64 + n * 16 + cw;
        const float bias = mb3[col];
#pragma unroll
        for (int m = 0; m < 2; ++m)
#pragma unroll
          for (int q = 0; q < 4; ++q) {
            const int row = mi * 32 + m * 16 + rq + q;
            const int2 vv = *reinterpret_cast<const int2*>(&verts[(size_t)(e0 + row) * 2]);
            const float v = acc[m][n][q] + bias;
            unsafeAtomicAdd(&summed[(size_t)vv.x * 128 + col], v);
            unsafeAtomicAdd(&summed[(size_t)vv.y * 128 + col], v);
          }
      }
    } else {
#pragma unroll
      for (int n = 0; n < 4; ++n) {
        const int col = ni * 64 + n * 16 + cw;
        const float bias = mb3[col];
#pragma unroll
        for (int m = 0; m < 2; ++m)
#pragma unroll
          for (int q = 0; q < 4; ++q) {
            const int row = mi * 32 + m * 16 + rq + q;
            msgs[(size_t)(e0 + row) * 128 + col] = f2bf(acc[m][n][q] + bias);
          }
      }
    }
  }
}

// Update MLP: 32 nodes per workgroup, 2 waves, NTW=8, single LDS buffer.
// LDS = 32*392*2 = 25088 B -> 6 blocks/CU. attention[n] = ns[n] - ns[n^2048].
template <bool GATHER>
__global__ __launch_bounds__(128, 3) void upd_kernel(
    const float* __restrict__ ns, const float* __restrict__ summed,
    const unsigned short* __restrict__ msgs, const int* __restrict__ cnt,
    const int* __restrict__ eidx, const unsigned short* __restrict__ wf,
    const float* __restrict__ ub1, const float* __restrict__ ub2,
    const float* __restrict__ ub3, float* __restrict__ out) {
  extern __shared__ unsigned short smem[];
  unsigned short* Xs = smem;  // [32][392]; X cols 0..383, then H 0..255

  const int tid = threadIdx.x;
  const int lane = tid & 63;
  const int w = tid >> 6;
  const int n0 = blockIdx.x * 32;

  // Phase 1: node | attention -> Xs; summed read (fallback) or eidx staging (CSR).
  for (int i = tid; i < 512; i += 128) {
    const int row = i >> 4;
    const int c = (i & 15) * 8;
    const int n = n0 + row;
    const float4* sA = reinterpret_cast<const float4*>(ns + (size_t)n * 128 + c);
    const float4 a0 = sA[0], a1 = sA[1];
    cvt_store8(&Xs[row * 392 + c], a0, a1);
    if constexpr (!GATHER) {
      const float4* sS = reinterpret_cast<const float4*>(summed + (size_t)n * 128 + c);
      cvt_store8(&Xs[row * 392 + 128 + c], sS[0], sS[1]);
    }
    const float4* sP = reinterpret_cast<const float4*>(ns + (size_t)(n ^ 2048) * 128 + c);
    const float4 p0 = sP[0], p1 = sP[1];
    float4 d0, d1;
    d0.x = a0.x - p0.x; d0.y = a0.y - p0.y; d0.z = a0.z - p0.z; d0.w = a0.w - p0.w;
    d1.x = a1.x - p1.x; d1.y = a1.y - p1.y; d1.z = a1.z - p1.z; d1.w = a1.w - p1.w;
    cvt_store8(&Xs[row * 392 + 256 + c], d0, d1);
  }

  if constexpr (GATHER) {
    // Stage this tile's eidx lists into Xs cols 128..255 (64 ints per row).
    for (int i = tid; i < 512; i += 128) {
      const int row = i >> 4;
      const int q4 = i & 15;
      reinterpret_cast<int4*>(&Xs[row * 392 + 128])[q4] =
          reinterpret_cast<const int4*>(&eidx[(size_t)(n0 + row) * 64])[q4];
    }
    __syncthreads();

    // 4 threads per node, 32 cols each; fp32 accumulate in registers.
    const int nl = tid >> 2;
    const int part = tid & 3;
    const int cn = min(cnt[n0 + nl], 64);
    const int* el = reinterpret_cast<const int*>(&Xs[nl * 392 + 128]);
    float acc[32];
#pragma unroll
    for (int k = 0; k < 32; ++k) acc[k] = 0.0f;
    for (int j = 0; j < cn; ++j) {
      const int e = el[j];
      const bf16x8* mp = reinterpret_cast<const bf16x8*>(&msgs[(size_t)e * 128 + part * 32]);
#pragma unroll
      for (int t = 0; t < 4; ++t) {
        const bf16x8 v = mp[t];
#pragma unroll
        for (int k = 0; k < 8; ++k) acc[t * 8 + k] += bf2f(v[k]);
      }
    }
    __syncthreads();  // all eidx LDS reads done before overwrite
#pragma unroll
    for (int t = 0; t < 4; ++t) {
      *reinterpret_cast<uint4*>(&Xs[nl * 392 + 128 + part * 32 + t * 8]) =
          make_uint4(cvtpk(acc[t * 8 + 0], acc[t * 8 + 1]), cvtpk(acc[t * 8 + 2], acc[t * 8 + 3]),
                     cvtpk(acc[t * 8 + 4], acc[t * 8 + 5]), cvtpk(acc[t * 8 + 6], acc[t * 8 + 7]));
    }
  }
  __syncthreads();

  const int cw = lane & 15;
  const int rq = (lane >> 4) * 4;

  // Layer 1: 384 -> 256, relu. Each wave: 128 output cols. H back into Xs.
  {
    f32x4 acc[2][8];
#pragma unroll
    for (int m = 0; m < 2; ++m)
#pragma unroll
      for (int n = 0; n < 8; ++n)
#pragma unroll
        for (int i = 0; i < 4; ++i) acc[m][n][i] = 0.0f;
    gemm_tile<2, 12, 8>(Xs, 392, wf + OF_UW1 + (size_t)(w * 8) * 12 * 512, acc, lane);
    __syncthreads();
#pragma unroll
    for (int n = 0; n < 8; ++n) {
      const int col = w * 128 + n * 16 + cw;
      const float bias = ub1[col];
#pragma unroll
      for (int m = 0; m < 2; ++m)
#pragma unroll
        for (int q = 0; q < 4; ++q) {
          const int row = m * 16 + rq + q;
          Xs[row * 392 + col] = f2bf(fmaxf(acc[m][n][q] + bias, 0.0f));
        }
    }
  }
  __syncthreads();

  // Layer 2: 256 -> 256, relu, in-place on Xs.
  {
    f32x4 acc[2][8];
#pragma unroll
    for (int m = 0; m < 2; ++m)
#pragma unroll
      for (int n = 0; n < 8; ++n)
#pragma unroll
        for (int i = 0; i < 4; ++i) acc[m][n][i] = 0.0f;
    gemm_tile<2, 8, 8>(Xs, 392, wf + OF_UW2 + (size_t)(w * 8) * 8 * 512, acc, lane);
    __syncthreads();
#pragma unroll
    for (int n = 0; n < 8; ++n) {
      const int col = w * 128 + n * 16 + cw;
      const float bias = ub2[col];
#pragma unroll
      for (int m = 0; m < 2; ++m)
#pragma unroll
        for (int q = 0; q < 4; ++q) {
          const int row = m * 16 + rq + q;
          Xs[row * 392 + col] = f2bf(fmaxf(acc[m][n][q] + bias, 0.0f));
        }
    }
  }
  __syncthreads();

  // Layer 3: 256 -> 128 -> out (fp32). Each wave: 64 output cols.
  {
    f32x4 acc[2][4];
#pragma unroll
    for (int m = 0; m < 2; ++m)
#pragma unroll
      for (int n = 0; n < 4; ++n)
#pragma unroll
        for (int i = 0; i < 4; ++i) acc[m][n][i] = 0.0f;
    gemm_tile<2, 8, 4>(Xs, 392, wf + OF_UW3 + (size_t)(w * 4) * 8 * 512, acc, lane);
#pragma unroll
    for (int n = 0; n < 4; ++n) {
      const int col = w * 64 + n * 16 + cw;
      const float bias = ub3[col];
#pragma unroll
      for (int m = 0; m < 2; ++m)
#pragma unroll
        for (int q = 0; q < 4; ++q) {
          const int row = m * 16 + rq + q;
          out[(size_t)(n0 + row) * 128 + col] = acc[m][n][q] + bias;
        }
    }
  }
}

extern "C" void kernel_launch(void* const* d_in, const int* in_sizes, int n_in,
                              void* d_out, int out_size, void* d_ws, size_t ws_size,
                              hipStream_t stream) {
  const float* ns   = (const float*)d_in[0];
  const float* edg  = (const float*)d_in[1];
  const int* verts  = (const int*)d_in[2];
  const float* mW1  = (const float*)d_in[3];
  const float* mb1  = (const float*)d_in[4];
  const float* mW2  = (const float*)d_in[5];
  const float* mb2  = (const float*)d_in[6];
  const float* mW3  = (const float*)d_in[7];
  const float* mb3  = (const float*)d_in[8];
  const float* uW1  = (const float*)d_in[9];
  const float* ub1  = (const float*)d_in[10];
  const float* uW2  = (const float*)d_in[11];
  const float* ub2  = (const float*)d_in[12];
  const float* uW3  = (const float*)d_in[13];
  const float* ub3  = (const float*)d_in[14];
  float* out = (float*)d_out;

  const int msg_lds = 64 * 328 * 2;  // 41984 B -> 3 blocks/CU
  const int upd_lds = 32 * 392 * 2;  // 25088 B -> 6 blocks/CU

  if (ws_size >= WS_NEED) {
    // CSR path: no fp32 scatter-atomics; bf16 node (and maybe edge) tables.
    unsigned short* msgs = (unsigned short*)d_ws;
    unsigned short* nsb  = (unsigned short*)((char*)d_ws + WS_NSB_OFF);
    int* eidx = (int*)((char*)d_ws + WS_EIDX_OFF);
    int* cnt  = (int*)((char*)d_ws + WS_CNT_OFF);
    unsigned short* wf = (unsigned short*)((char*)d_ws + WS_WF_OFF);
    const bool has_eb = ws_size >= WS_NEED2;
    unsigned short* eb = has_eb ? (unsigned short*)((char*)d_ws + WS_EB_OFF) : nullptr;

    (void)hipMemsetAsync(cnt, 0, WS_CNT_BYTES, stream);
    prep_weights<<<736, 64, 0, stream>>>(mW1, mW2, mW3, uW1, uW2, uW3, wf);
    prep_data<<<has_eb ? 20480 : 4096, 256, 0, stream>>>(ns, nsb, edg, eb);
    fill_csr<<<2 * NEDGES / 256, 256, 0, stream>>>(verts, cnt, eidx);
    if (has_eb)
      msg_kernel<2><<<NEDGES / 64, 256, msg_lds, stream>>>(
          ns, nsb, edg, eb, verts, wf, mb1, mb2, mb3, nullptr, msgs);
    else
      msg_kernel<1><<<NEDGES / 64, 256, msg_lds, stream>>>(
          ns, nsb, edg, nullptr, verts, wf, mb1, mb2, mb3, nullptr, msgs);
    upd_kernel<true><<<NNODES / 32, 128, upd_lds, stream>>>(
        ns, nullptr, msgs, cnt, eidx, wf, ub1, ub2, ub3, out);
  } else {
    // Fallback: atomic path.
    float* summed = (float*)d_ws;
    unsigned short* wf = (unsigned short*)((char*)d_ws + WS_SUMMED_BYTES);

    (void)hipMemsetAsync(summed, 0, WS_SUMMED_BYTES, stream);
    prep_weights<<<736, 64, 0, stream>>>(mW1, mW2, mW3, uW1, uW2, uW3, wf);
    msg_kernel<0><<<NEDGES / 64, 256, msg_lds, stream>>>(
        ns, nullptr, edg, nullptr, verts, wf, mb1, mb2, mb3, summed, nullptr);
    upd_kernel<false><<<NNODES / 32, 128, upd_lds, stream>>>(
        ns, summed, nullptr, nullptr, nullptr, wf, ub1, ub2, ub3, out);
  }
}

// Round 14
// 544.257 us; speedup vs baseline: 1.1118x; 1.1118x over previous
//
#include <hip/hip_runtime.h>

// Problem constants
#define NNODES 65536
#define NEDGES 524288

typedef short bf16x8 __attribute__((ext_vector_type(8)));
typedef float f32x4 __attribute__((ext_vector_type(4)));

// Packed-weight fragment offsets (in bf16 elements) within the weight region.
// Fragment layout per matrix (K x NC): [n_tile][k_tile][lane][8], 512 bf16 per fragment.
#define OF_MW1 0        // 320x256: KT=10, NT=16 -> 81920
#define OF_MW2 81920    // 256x256: KT=8,  NT=16 -> 65536
#define OF_MW3 147456   // 256x128: KT=8,  NT=8  -> 32768
#define OF_UW1 180224   // 384x256: KT=12, NT=16 -> 98304
#define OF_UW2 278528   // 256x256: KT=8,  NT=16 -> 65536
#define OF_UW3 344064   // 256x128: KT=8,  NT=8  -> 32768
#define WF_BYTES (376832 * 2)

// Big-workspace layout (CSR path, tier 1)
#define WS_MSGS_BYTES ((size_t)NEDGES * 128 * 2)          // 134217728 (bf16)
#define WS_NSB_OFF    WS_MSGS_BYTES
#define WS_NSB_BYTES  ((size_t)NNODES * 128 * 2)          // 16777216 (bf16 node table)
#define WS_EIDX_OFF   (WS_NSB_OFF + WS_NSB_BYTES)
#define WS_EIDX_BYTES ((size_t)NNODES * 64 * 4)           // 16777216
#define WS_CNT_OFF    (WS_EIDX_OFF + WS_EIDX_BYTES)
#define WS_CNT_BYTES  ((size_t)NNODES * 4)                // 262144
#define WS_WF_OFF     (WS_CNT_OFF + WS_CNT_BYTES)
#define WS_NEED       (WS_WF_OFF + WF_BYTES)
// Tier 2 adds a bf16 edge table at the end.
#define WS_EB_OFF     WS_NEED
#define WS_EB_BYTES   ((size_t)NEDGES * 64 * 2)           // 67108864
#define WS_NEED2      (WS_EB_OFF + WS_EB_BYTES)

// Fallback layout (atomic path)
#define WS_SUMMED_BYTES ((size_t)NNODES * 128 * 4)

__device__ __forceinline__ unsigned short f2bf(float x) {
  unsigned int u = __float_as_uint(x);
  return (unsigned short)((u + 0x7FFFu + ((u >> 16) & 1u)) >> 16);  // RNE
}

__device__ __forceinline__ float bf2f(short s) {
  return __uint_as_float((unsigned int)(unsigned short)s << 16);
}

// v_cvt_pk_bf16_f32 (RNE): result.lo16 = bf16(a), result.hi16 = bf16(b).
__device__ __forceinline__ unsigned int cvtpk(float a, float b) {
  unsigned int r;
  asm("v_cvt_pk_bf16_f32 %0, %1, %2" : "=v"(r) : "v"(a), "v"(b));
  return r;
}

// Pack 8 f32 -> 8 bf16 (one 16B store) via 4 packed converts.
__device__ __forceinline__ void cvt_store8(unsigned short* p, float4 a, float4 b) {
  *reinterpret_cast<uint4*>(p) =
      make_uint4(cvtpk(a.x, a.y), cvtpk(a.z, a.w), cvtpk(b.x, b.y), cvtpk(b.z, b.w));
}

// Async global->LDS 16B copy: per-lane global src, wave-uniform LDS base + lane*16.
__device__ __forceinline__ void gload_lds16(const void* g, void* l) {
  __builtin_amdgcn_global_load_lds(
      (const __attribute__((address_space(1))) void*)g,
      (__attribute__((address_space(3))) void*)l, 16, 0, 0);
}

// Tile GEMM from row-major LDS with 1-deep register prefetch (legacy msg + upd).
template <int MT, int KT, int NTW>
__device__ __forceinline__ void gemm_tile(const unsigned short* A, const int lda,
                                          const unsigned short* Wf,
                                          f32x4 (&acc)[MT][NTW], const int lane) {
  const int ar = lane & 15;
  const int ak = (lane >> 4) << 3;
  bf16x8 bcur[NTW], acur[MT];
#pragma unroll
  for (int n = 0; n < NTW; ++n)
    bcur[n] = *reinterpret_cast<const bf16x8*>(&Wf[(size_t)(n * KT) * 512 + lane * 8]);
#pragma unroll
  for (int m = 0; m < MT; ++m)
    acur[m] = *reinterpret_cast<const bf16x8*>(&A[(m * 16 + ar) * lda + ak]);
#pragma unroll
  for (int kt = 0; kt < KT; ++kt) {
    bf16x8 bnxt[NTW], anxt[MT];
    if (kt + 1 < KT) {
#pragma unroll
      for (int n = 0; n < NTW; ++n)
        bnxt[n] = *reinterpret_cast<const bf16x8*>(
            &Wf[(size_t)(n * KT + kt + 1) * 512 + lane * 8]);
#pragma unroll
      for (int m = 0; m < MT; ++m)
        anxt[m] = *reinterpret_cast<const bf16x8*>(
            &A[(m * 16 + ar) * lda + (kt + 1) * 32 + ak]);
    }
#pragma unroll
    for (int n = 0; n < NTW; ++n)
#pragma unroll
      for (int m = 0; m < MT; ++m)
        acc[m][n] = __builtin_amdgcn_mfma_f32_16x16x32_bf16(acur[m], bcur[n], acc[m][n], 0, 0, 0);
    if (kt + 1 < KT) {
#pragma unroll
      for (int n = 0; n < NTW; ++n) bcur[n] = bnxt[n];
#pragma unroll
      for (int m = 0; m < MT; ++m) acur[m] = anxt[m];
    }
  }
}

// Tile GEMM from FRAGMENT-ORDER LDS: A frag(m,kt) at FB + (m*KT+kt)*512 + lane*8.
// Contiguous per lane (conflict-free ds_read_b128, compile-time offsets).
template <int MT, int KT, int NTW>
__device__ __forceinline__ void gemm_tile_frag(const unsigned short* FB,
                                               const unsigned short* Wf,
                                               f32x4 (&acc)[MT][NTW], const int lane) {
  bf16x8 bcur[NTW], acur[MT];
#pragma unroll
  for (int n = 0; n < NTW; ++n)
    bcur[n] = *reinterpret_cast<const bf16x8*>(&Wf[(size_t)(n * KT) * 512 + lane * 8]);
#pragma unroll
  for (int m = 0; m < MT; ++m)
    acur[m] = *reinterpret_cast<const bf16x8*>(&FB[(m * KT) * 512 + lane * 8]);
#pragma unroll
  for (int kt = 0; kt < KT; ++kt) {
    bf16x8 bnxt[NTW], anxt[MT];
    if (kt + 1 < KT) {
#pragma unroll
      for (int n = 0; n < NTW; ++n)
        bnxt[n] = *reinterpret_cast<const bf16x8*>(
            &Wf[(size_t)(n * KT + kt + 1) * 512 + lane * 8]);
#pragma unroll
      for (int m = 0; m < MT; ++m)
        anxt[m] = *reinterpret_cast<const bf16x8*>(&FB[(m * KT + kt + 1) * 512 + lane * 8]);
    }
#pragma unroll
    for (int n = 0; n < NTW; ++n)
#pragma unroll
      for (int m = 0; m < MT; ++m)
        acc[m][n] = __builtin_amdgcn_mfma_f32_16x16x32_bf16(acur[m], bcur[n], acc[m][n], 0, 0, 0);
    if (kt + 1 < KT) {
#pragma unroll
      for (int n = 0; n < NTW; ++n) bcur[n] = bnxt[n];
#pragma unroll
      for (int m = 0; m < MT; ++m) acur[m] = anxt[m];
    }
  }
}

// Convert all six weight matrices into MFMA B-fragment order (bf16).
__global__ void prep_weights(const float* __restrict__ mW1, const float* __restrict__ mW2,
                             const float* __restrict__ mW3, const float* __restrict__ uW1,
                             const float* __restrict__ uW2, const float* __restrict__ uW3,
                             unsigned short* __restrict__ wf) {
  const int f = blockIdx.x;
  const int lane = threadIdx.x;
  const float* W; int NC, KT, fl, base;
  if (f < 160)      { W = mW1; NC = 256; KT = 10; fl = f;       base = OF_MW1; }
  else if (f < 288) { W = mW2; NC = 256; KT = 8;  fl = f - 160; base = OF_MW2; }
  else if (f < 352) { W = mW3; NC = 128; KT = 8;  fl = f - 288; base = OF_MW3; }
  else if (f < 544) { W = uW1; NC = 256; KT = 12; fl = f - 352; base = OF_UW1; }
  else if (f < 672) { W = uW2; NC = 256; KT = 8;  fl = f - 544; base = OF_UW2; }
  else              { W = uW3; NC = 128; KT = 8;  fl = f - 672; base = OF_UW3; }
  const int n_t = fl / KT;
  const int k_t = fl % KT;
  const int col = n_t * 16 + (lane & 15);
  const int krow = k_t * 32 + ((lane >> 4) << 3);
  unsigned short* dst = wf + base + (size_t)fl * 512 + lane * 8;
#pragma unroll
  for (int e = 0; e < 8; ++e) dst[e] = f2bf(W[(size_t)(krow + e) * NC + col]);
}

// One launch: bf16 node table + (optional) bf16 edge table + CSR bucket fill.
__global__ void prep_all(const float* __restrict__ ns, unsigned short* __restrict__ nsb,
                         const float* __restrict__ edg, unsigned short* __restrict__ eb,
                         const int* __restrict__ verts, int* __restrict__ cnt,
                         int* __restrict__ eidx, const int csr_base) {
  const int b = blockIdx.x;
  if (b < 4096) {
    const size_t i = ((size_t)b * 256 + threadIdx.x) * 8;
    const float4* s = reinterpret_cast<const float4*>(ns + i);
    cvt_store8(&nsb[i], s[0], s[1]);
  } else if (b < csr_base) {
    const size_t i = ((size_t)(b - 4096) * 256 + threadIdx.x) * 8;
    const float4* s = reinterpret_cast<const float4*>(edg + i);
    cvt_store8(&eb[i], s[0], s[1]);
  } else {
    const int k = (b - csr_base) * 256 + threadIdx.x;
    const int v = verts[k];
    const int slot = atomicAdd(&cnt[v], 1);
    if (slot < 64) eidx[(size_t)v * 64 + slot] = k >> 1;  // message row = edge id
  }
}

// Message MLP, FRAGMENT-NATIVE (tier 2). 64 edges/block, 4 waves (1M x 4N).
// X and H live in LDS in MFMA-fragment order: frag(m,kt) = FB + (m*KT+kt)*512 + lane*8,
// elem(lane,j) = X[m*16 + (lane&15)][kt*32 + (lane>>4)*8 + j].
// Staging: 10 global_load_lds per wave (per-lane gather src, linear LDS dest).
// LDS = 4*10*512*2 = 40960 B -> 4 blocks/CU.
__global__ __launch_bounds__(256, 4) void msg_frag_kernel(
    const unsigned short* __restrict__ nsb, const unsigned short* __restrict__ eb,
    const int* __restrict__ verts, const unsigned short* __restrict__ wf,
    const float* __restrict__ mb1, const float* __restrict__ mb2,
    const float* __restrict__ mb3, unsigned short* __restrict__ msgs) {
  extern __shared__ unsigned short smem[];
  unsigned short* FB = smem;  // [4][10][512] frags; X then (in-place) H as [4][8][512]

  const int tid = threadIdx.x;
  const int lane = tid & 63;
  const int w = tid >> 6;
  const int e0 = blockIdx.x * 64;

  // Staging: wave w fills frags (m=w, kt=0..9) with async 16B copies.
  {
    const int row = w * 16 + (lane & 15);
    const int ko = (lane >> 4) << 3;
    const int2 vv = *reinterpret_cast<const int2*>(&verts[(size_t)(e0 + row) * 2]);
    const unsigned short* ni_p = nsb + (size_t)vv.x * 128 + ko;
    const unsigned short* nj_p = nsb + (size_t)vv.y * 128 + ko;
    const unsigned short* eg_p = eb + (size_t)(e0 + row) * 64 + ko;
    unsigned short* fb_w = FB + w * 10 * 512;
#pragma unroll
    for (int kt = 0; kt < 4; ++kt)
      gload_lds16(ni_p + kt * 32, fb_w + kt * 512);
#pragma unroll
    for (int kt = 0; kt < 4; ++kt)
      gload_lds16(nj_p + kt * 32, fb_w + (4 + kt) * 512);
#pragma unroll
    for (int kt = 0; kt < 2; ++kt)
      gload_lds16(eg_p + kt * 32, fb_w + (8 + kt) * 512);
  }
  __syncthreads();

  const int cw = lane & 15;
  const int rq = (lane >> 4) * 4;

  // Layer 1: 320 -> 256, relu. Wave w: cols w*64..w*64+63. H -> frag order in FB.
  {
    f32x4 acc[4][4];
#pragma unroll
    for (int m = 0; m < 4; ++m)
#pragma unroll
      for (int n = 0; n < 4; ++n)
#pragma unroll
        for (int i = 0; i < 4; ++i) acc[m][n][i] = 0.0f;
    gemm_tile_frag<4, 10, 4>(FB, wf + OF_MW1 + (size_t)(w * 4) * 10 * 512, acc, lane);
    __syncthreads();  // all X-frag reads done before overwrite
#pragma unroll
    for (int n = 0; n < 4; ++n) {
      const int col = w * 64 + n * 16 + cw;
      const float bias = mb1[col];
      const int kt2 = col >> 5;
      const int lb = ((col >> 3) & 3) << 4;
      const int j = col & 7;
#pragma unroll
      for (int m = 0; m < 4; ++m)
#pragma unroll
        for (int q = 0; q < 4; ++q)
          FB[(m * 8 + kt2) * 512 + (lb + rq + q) * 8 + j] =
              f2bf(fmaxf(acc[m][n][q] + bias, 0.0f));
    }
  }
  __syncthreads();

  // Layer 2: 256 -> 256, relu, in-place on H frags.
  {
    f32x4 acc[4][4];
#pragma unroll
    for (int m = 0; m < 4; ++m)
#pragma unroll
      for (int n = 0; n < 4; ++n)
#pragma unroll
        for (int i = 0; i < 4; ++i) acc[m][n][i] = 0.0f;
    gemm_tile_frag<4, 8, 4>(FB, wf + OF_MW2 + (size_t)(w * 4) * 8 * 512, acc, lane);
    __syncthreads();
#pragma unroll
    for (int n = 0; n < 4; ++n) {
      const int col = w * 64 + n * 16 + cw;
      const float bias = mb2[col];
      const int kt2 = col >> 5;
      const int lb = ((col >> 3) & 3) << 4;
      const int j = col & 7;
#pragma unroll
      for (int m = 0; m < 4; ++m)
#pragma unroll
        for (int q = 0; q < 4; ++q)
          FB[(m * 8 + kt2) * 512 + (lb + rq + q) * 8 + j] =
              f2bf(fmaxf(acc[m][n][q] + bias, 0.0f));
    }
  }
  __syncthreads();

  // Layer 3: 256 -> 128, straight from accumulators to msgs (no LDS, no barrier).
  {
    f32x4 acc[4][2];
#pragma unroll
    for (int m = 0; m < 4; ++m)
#pragma unroll
      for (int n = 0; n < 2; ++n)
#pragma unroll
        for (int i = 0; i < 4; ++i) acc[m][n][i] = 0.0f;
    gemm_tile_frag<4, 8, 2>(FB, wf + OF_MW3 + (size_t)(w * 2) * 8 * 512, acc, lane);
#pragma unroll
    for (int n = 0; n < 2; ++n) {
      const int col = w * 32 + n * 16 + cw;
      const float bias = mb3[col];
#pragma unroll
      for (int m = 0; m < 4; ++m)
#pragma unroll
        for (int q = 0; q < 4; ++q) {
          const int row = m * 16 + rq + q;
          msgs[(size_t)(e0 + row) * 128 + col] = f2bf(acc[m][n][q] + bias);
        }
    }
  }
}

// Legacy message MLP (tiers 0/1): round-12 structure, row-major [64][328] LDS.
// LDS = 64*328*2 = 41984 B -> 3 blocks/CU.
template <bool ATOMIC>
__global__ __launch_bounds__(256, 3) void msg_kernel(
    const float* __restrict__ ns, const unsigned short* __restrict__ nsb,
    const float* __restrict__ edg, const int* __restrict__ verts,
    const unsigned short* __restrict__ wf, const float* __restrict__ mb1,
    const float* __restrict__ mb2, const float* __restrict__ mb3,
    float* __restrict__ summed, unsigned short* __restrict__ msgs) {
  extern __shared__ unsigned short smem[];
  unsigned short* Xs = smem;  // [64][328] bf16; X cols 0..319, then H 0..255

  const int tid = threadIdx.x;
  const int lane = tid & 63;
  const int w = tid >> 6;
  const int e0 = blockIdx.x * 64;

  {
    const int r = tid >> 4;
    const int c = (tid & 15) * 8;
#pragma unroll
    for (int p = 0; p < 4; ++p) {
      const int row = p * 16 + r;
      const int2 vv = *reinterpret_cast<const int2*>(&verts[(size_t)(e0 + row) * 2]);
      if constexpr (ATOMIC) {
        const float4* s0 = reinterpret_cast<const float4*>(ns + (size_t)vv.x * 128 + c);
        cvt_store8(&Xs[row * 328 + c], s0[0], s0[1]);
        const float4* s1 = reinterpret_cast<const float4*>(ns + (size_t)vv.y * 128 + c);
        cvt_store8(&Xs[row * 328 + 128 + c], s1[0], s1[1]);
      } else {
        *reinterpret_cast<bf16x8*>(&Xs[row * 328 + c]) =
            *reinterpret_cast<const bf16x8*>(&nsb[(size_t)vv.x * 128 + c]);
        *reinterpret_cast<bf16x8*>(&Xs[row * 328 + 128 + c]) =
            *reinterpret_cast<const bf16x8*>(&nsb[(size_t)vv.y * 128 + c]);
      }
    }
#pragma unroll
    for (int i = tid; i < 512; i += 256) {
      const int row = i >> 3;
      const int cc = (i & 7) * 8;
      const float4* s2 = reinterpret_cast<const float4*>(edg + (size_t)(e0 + row) * 64 + cc);
      cvt_store8(&Xs[row * 328 + 256 + cc], s2[0], s2[1]);
    }
  }
  __syncthreads();

  const int cw = lane & 15;
  const int rq = (lane >> 4) * 4;

  {
    f32x4 acc[4][4];
#pragma unroll
    for (int m = 0; m < 4; ++m)
#pragma unroll
      for (int n = 0; n < 4; ++n)
#pragma unroll
        for (int i = 0; i < 4; ++i) acc[m][n][i] = 0.0f;
    gemm_tile<4, 10, 4>(Xs, 328, wf + OF_MW1 + (size_t)(w * 4) * 10 * 512, acc, lane);
    __syncthreads();
#pragma unroll
    for (int n = 0; n < 4; ++n) {
      const int col = w * 64 + n * 16 + cw;
      const float bias = mb1[col];
#pragma unroll
      for (int m = 0; m < 4; ++m)
#pragma unroll
        for (int q = 0; q < 4; ++q) {
          const int row = m * 16 + rq + q;
          Xs[row * 328 + col] = f2bf(fmaxf(acc[m][n][q] + bias, 0.0f));
        }
    }
  }
  __syncthreads();

  {
    f32x4 acc[4][4];
#pragma unroll
    for (int m = 0; m < 4; ++m)
#pragma unroll
      for (int n = 0; n < 4; ++n)
#pragma unroll
        for (int i = 0; i < 4; ++i) acc[m][n][i] = 0.0f;
    gemm_tile<4, 8, 4>(Xs, 328, wf + OF_MW2 + (size_t)(w * 4) * 8 * 512, acc, lane);
    __syncthreads();
#pragma unroll
    for (int n = 0; n < 4; ++n) {
      const int col = w * 64 + n * 16 + cw;
      const float bias = mb2[col];
#pragma unroll
      for (int m = 0; m < 4; ++m)
#pragma unroll
        for (int q = 0; q < 4; ++q) {
          const int row = m * 16 + rq + q;
          Xs[row * 328 + col] = f2bf(fmaxf(acc[m][n][q] + bias, 0.0f));
        }
    }
  }
  __syncthreads();

  {
    f32x4 acc[4][2];
#pragma unroll
    for (int m = 0; m < 4; ++m)
#pragma unroll
      for (int n = 0; n < 2; ++n)
#pragma unroll
        for (int i = 0; i < 4; ++i) acc[m][n][i] = 0.0f;
    gemm_tile<4, 8, 2>(Xs, 328, wf + OF_MW3 + (size_t)(w * 2) * 8 * 512, acc, lane);

    if constexpr (ATOMIC) {
#pragma unroll
      for (int n = 0; n < 2; ++n) {
        const int col = w * 32 + n * 16 + cw;
        const float bias = mb3[col];
#pragma unroll
        for (int m = 0; m < 4; ++m)
#pragma unroll
          for (int q = 0; q < 4; ++q) {
            const int row = m * 16 + rq + q;
            const int2 vv = *reinterpret_cast<const int2*>(&verts[(size_t)(e0 + row) * 2]);
            const float v = acc[m][n][q] + bias;
            unsafeAtomicAdd(&summed[(size_t)vv.x * 128 + col], v);
            unsafeAtomicAdd(&summed[(size_t)vv.y * 128 + col], v);
          }
      }
    } else {
#pragma unroll
      for (int n = 0; n < 2; ++n) {
        const int col = w * 32 + n * 16 + cw;
        const float bias = mb3[col];
#pragma unroll
        for (int m = 0; m < 4; ++m)
#pragma unroll
          for (int q = 0; q < 4; ++q) {
            const int row = m * 16 + rq + q;
            msgs[(size_t)(e0 + row) * 128 + col] = f2bf(acc[m][n][q] + bias);
          }
      }
    }
  }
}

// Update MLP: 32 nodes per workgroup, 2 waves, NTW=8, single LDS buffer.
// LDS = 32*392*2 = 25088 B -> 6 blocks/CU. attention[n] = ns[n] - ns[n^2048].
template <bool GATHER>
__global__ __launch_bounds__(128, 3) void upd_kernel(
    const float* __restrict__ ns, const float* __restrict__ summed,
    const unsigned short* __restrict__ msgs, const int* __restrict__ cnt,
    const int* __restrict__ eidx, const unsigned short* __restrict__ wf,
    const float* __restrict__ ub1, const float* __restrict__ ub2,
    const float* __restrict__ ub3, float* __restrict__ out) {
  extern __shared__ unsigned short smem[];
  unsigned short* Xs = smem;  // [32][392]; X cols 0..383, then H 0..255

  const int tid = threadIdx.x;
  const int lane = tid & 63;
  const int w = tid >> 6;
  const int n0 = blockIdx.x * 32;

  for (int i = tid; i < 512; i += 128) {
    const int row = i >> 4;
    const int c = (i & 15) * 8;
    const int n = n0 + row;
    const float4* sA = reinterpret_cast<const float4*>(ns + (size_t)n * 128 + c);
    const float4 a0 = sA[0], a1 = sA[1];
    cvt_store8(&Xs[row * 392 + c], a0, a1);
    if constexpr (!GATHER) {
      const float4* sS = reinterpret_cast<const float4*>(summed + (size_t)n * 128 + c);
      cvt_store8(&Xs[row * 392 + 128 + c], sS[0], sS[1]);
    }
    const float4* sP = reinterpret_cast<const float4*>(ns + (size_t)(n ^ 2048) * 128 + c);
    const float4 p0 = sP[0], p1 = sP[1];
    float4 d0, d1;
    d0.x = a0.x - p0.x; d0.y = a0.y - p0.y; d0.z = a0.z - p0.z; d0.w = a0.w - p0.w;
    d1.x = a1.x - p1.x; d1.y = a1.y - p1.y; d1.z = a1.z - p1.z; d1.w = a1.w - p1.w;
    cvt_store8(&Xs[row * 392 + 256 + c], d0, d1);
  }

  if constexpr (GATHER) {
    for (int i = tid; i < 512; i += 128) {
      const int row = i >> 4;
      const int q4 = i & 15;
      reinterpret_cast<int4*>(&Xs[row * 392 + 128])[q4] =
          reinterpret_cast<const int4*>(&eidx[(size_t)(n0 + row) * 64])[q4];
    }
    __syncthreads();

    const int nl = tid >> 2;
    const int part = tid & 3;
    const int cn = min(cnt[n0 + nl], 64);
    const int* el = reinterpret_cast<const int*>(&Xs[nl * 392 + 128]);
    float acc[32];
#pragma unroll
    for (int k = 0; k < 32; ++k) acc[k] = 0.0f;
    for (int j = 0; j < cn; ++j) {
      const int e = el[j];
      const bf16x8* mp = reinterpret_cast<const bf16x8*>(&msgs[(size_t)e * 128 + part * 32]);
#pragma unroll
      for (int t = 0; t < 4; ++t) {
        const bf16x8 v = mp[t];
#pragma unroll
        for (int k = 0; k < 8; ++k) acc[t * 8 + k] += bf2f(v[k]);
      }
    }
    __syncthreads();
#pragma unroll
    for (int t = 0; t < 4; ++t) {
      *reinterpret_cast<uint4*>(&Xs[nl * 392 + 128 + part * 32 + t * 8]) =
          make_uint4(cvtpk(acc[t * 8 + 0], acc[t * 8 + 1]), cvtpk(acc[t * 8 + 2], acc[t * 8 + 3]),
                     cvtpk(acc[t * 8 + 4], acc[t * 8 + 5]), cvtpk(acc[t * 8 + 6], acc[t * 8 + 7]));
    }
  }
  __syncthreads();

  const int cw = lane & 15;
  const int rq = (lane >> 4) * 4;

  {
    f32x4 acc[2][8];
#pragma unroll
    for (int m = 0; m < 2; ++m)
#pragma unroll
      for (int n = 0; n < 8; ++n)
#pragma unroll
        for (int i = 0; i < 4; ++i) acc[m][n][i] = 0.0f;
    gemm_tile<2, 12, 8>(Xs, 392, wf + OF_UW1 + (size_t)(w * 8) * 12 * 512, acc, lane);
    __syncthreads();
#pragma unroll
    for (int n = 0; n < 8; ++n) {
      const int col = w * 128 + n * 16 + cw;
      const float bias = ub1[col];
#pragma unroll
      for (int m = 0; m < 2; ++m)
#pragma unroll
        for (int q = 0; q < 4; ++q) {
          const int row = m * 16 + rq + q;
          Xs[row * 392 + col] = f2bf(fmaxf(acc[m][n][q] + bias, 0.0f));
        }
    }
  }
  __syncthreads();

  {
    f32x4 acc[2][8];
#pragma unroll
    for (int m = 0; m < 2; ++m)
#pragma unroll
      for (int n = 0; n < 8; ++n)
#pragma unroll
        for (int i = 0; i < 4; ++i) acc[m][n][i] = 0.0f;
    gemm_tile<2, 8, 8>(Xs, 392, wf + OF_UW2 + (size_t)(w * 8) * 8 * 512, acc, lane);
    __syncthreads();
#pragma unroll
    for (int n = 0; n < 8; ++n) {
      const int col = w * 128 + n * 16 + cw;
      const float bias = ub2[col];
#pragma unroll
      for (int m = 0; m < 2; ++m)
#pragma unroll
        for (int q = 0; q < 4; ++q) {
          const int row = m * 16 + rq + q;
          Xs[row * 392 + col] = f2bf(fmaxf(acc[m][n][q] + bias, 0.0f));
        }
    }
  }
  __syncthreads();

  {
    f32x4 acc[2][4];
#pragma unroll
    for (int m = 0; m < 2; ++m)
#pragma unroll
      for (int n = 0; n < 4; ++n)
#pragma unroll
        for (int i = 0; i < 4; ++i) acc[m][n][i] = 0.0f;
    gemm_tile<2, 8, 4>(Xs, 392, wf + OF_UW3 + (size_t)(w * 4) * 8 * 512, acc, lane);
#pragma unroll
    for (int n = 0; n < 4; ++n) {
      const int col = w * 64 + n * 16 + cw;
      const float bias = ub3[col];
#pragma unroll
      for (int m = 0; m < 2; ++m)
#pragma unroll
        for (int q = 0; q < 4; ++q) {
          const int row = m * 16 + rq + q;
          out[(size_t)(n0 + row) * 128 + col] = acc[m][n][q] + bias;
        }
    }
  }
}

extern "C" void kernel_launch(void* const* d_in, const int* in_sizes, int n_in,
                              void* d_out, int out_size, void* d_ws, size_t ws_size,
                              hipStream_t stream) {
  const float* ns   = (const float*)d_in[0];
  const float* edg  = (const float*)d_in[1];
  const int* verts  = (const int*)d_in[2];
  const float* mW1  = (const float*)d_in[3];
  const float* mb1  = (const float*)d_in[4];
  const float* mW2  = (const float*)d_in[5];
  const float* mb2  = (const float*)d_in[6];
  const float* mW3  = (const float*)d_in[7];
  const float* mb3  = (const float*)d_in[8];
  const float* uW1  = (const float*)d_in[9];
  const float* ub1  = (const float*)d_in[10];
  const float* uW2  = (const float*)d_in[11];
  const float* ub2  = (const float*)d_in[12];
  const float* uW3  = (const float*)d_in[13];
  const float* ub3  = (const float*)d_in[14];
  float* out = (float*)d_out;

  const int frag_lds = 4 * 10 * 512 * 2;  // 40960 B -> 4 blocks/CU
  const int msg_lds  = 64 * 328 * 2;      // 41984 B -> 3 blocks/CU
  const int upd_lds  = 32 * 392 * 2;      // 25088 B -> 6 blocks/CU

  if (ws_size >= WS_NEED) {
    unsigned short* msgs = (unsigned short*)d_ws;
    unsigned short* nsb  = (unsigned short*)((char*)d_ws + WS_NSB_OFF);
    int* eidx = (int*)((char*)d_ws + WS_EIDX_OFF);
    int* cnt  = (int*)((char*)d_ws + WS_CNT_OFF);
    unsigned short* wf = (unsigned short*)((char*)d_ws + WS_WF_OFF);
    const bool has_eb = ws_size >= WS_NEED2;
    unsigned short* eb = has_eb ? (unsigned short*)((char*)d_ws + WS_EB_OFF) : nullptr;
    const int csr_base = has_eb ? 20480 : 4096;

    (void)hipMemsetAsync(cnt, 0, WS_CNT_BYTES, stream);
    prep_weights<<<736, 64, 0, stream>>>(mW1, mW2, mW3, uW1, uW2, uW3, wf);
    prep_all<<<csr_base + 4096, 256, 0, stream>>>(ns, nsb, edg, eb, verts, cnt, eidx, csr_base);
    if (has_eb)
      msg_frag_kernel<<<NEDGES / 64, 256, frag_lds, stream>>>(
          nsb, eb, verts, wf, mb1, mb2, mb3, msgs);
    else
      msg_kernel<false><<<NEDGES / 64, 256, msg_lds, stream>>>(
          ns, nsb, edg, verts, wf, mb1, mb2, mb3, nullptr, msgs);
    upd_kernel<true><<<NNODES / 32, 128, upd_lds, stream>>>(
        ns, nullptr, msgs, cnt, eidx, wf, ub1, ub2, ub3, out);
  } else {
    float* summed = (float*)d_ws;
    unsigned short* wf = (unsigned short*)((char*)d_ws + WS_SUMMED_BYTES);

    (void)hipMemsetAsync(summed, 0, WS_SUMMED_BYTES, stream);
    prep_weights<<<736, 64, 0, stream>>>(mW1, mW2, mW3, uW1, uW2, uW3, wf);
    msg_kernel<true><<<NEDGES / 64, 256, msg_lds, stream>>>(
        ns, nullptr, edg, verts, wf, mb1, mb2, mb3, summed, nullptr);
    upd_kernel<false><<<NNODES / 32, 128, upd_lds, stream>>>(
        ns, summed, nullptr, nullptr, nullptr, wf, ub1, ub2, ub3, out);
  }
}

// Round 15
// 494.226 us; speedup vs baseline: 1.2243x; 1.1012x over previous
//
#include <hip/hip_runtime.h>

// Problem constants
#define NNODES 65536
#define NEDGES 524288

typedef short bf16x8 __attribute__((ext_vector_type(8)));
typedef float f32x4 __attribute__((ext_vector_type(4)));

// Packed-weight fragment offsets (in bf16 elements) within the weight region.
// Fragment layout per matrix (K x NC): [n_tile][k_tile][lane][8], 512 bf16 per fragment.
#define OF_MW1 0        // 320x256: KT=10, NT=16 -> 81920
#define OF_MW2 81920    // 256x256: KT=8,  NT=16 -> 65536
#define OF_MW3 147456   // 256x128: KT=8,  NT=8  -> 32768
#define OF_UW1 180224   // 384x256: KT=12, NT=16 -> 98304
#define OF_UW2 278528   // 256x256: KT=8,  NT=16 -> 65536
#define OF_UW3 344064   // 256x128: KT=8,  NT=8  -> 32768
#define WF_BYTES (376832 * 2)

// Big-workspace layout (CSR path, tier 1)
#define WS_MSGS_BYTES ((size_t)NEDGES * 128 * 2)          // 134217728 (bf16)
#define WS_NSB_OFF    WS_MSGS_BYTES
#define WS_NSB_BYTES  ((size_t)NNODES * 128 * 2)          // 16777216 (bf16 node table)
#define WS_EIDX_OFF   (WS_NSB_OFF + WS_NSB_BYTES)
#define WS_EIDX_BYTES ((size_t)NNODES * 64 * 4)           // 16777216
#define WS_CNT_OFF    (WS_EIDX_OFF + WS_EIDX_BYTES)
#define WS_CNT_BYTES  ((size_t)NNODES * 4)                // 262144
#define WS_WF_OFF     (WS_CNT_OFF + WS_CNT_BYTES)
#define WS_NEED       (WS_WF_OFF + WF_BYTES)
// Tier 2 adds a bf16 edge table at the end.
#define WS_EB_OFF     WS_NEED
#define WS_EB_BYTES   ((size_t)NEDGES * 64 * 2)           // 67108864
#define WS_NEED2      (WS_EB_OFF + WS_EB_BYTES)

// Fallback layout (atomic path)
#define WS_SUMMED_BYTES ((size_t)NNODES * 128 * 4)

__device__ __forceinline__ unsigned short f2bf(float x) {
  unsigned int u = __float_as_uint(x);
  return (unsigned short)((u + 0x7FFFu + ((u >> 16) & 1u)) >> 16);  // RNE
}

__device__ __forceinline__ float bf2f(short s) {
  return __uint_as_float((unsigned int)(unsigned short)s << 16);
}

// v_cvt_pk_bf16_f32 (RNE): result.lo16 = bf16(a), result.hi16 = bf16(b).
__device__ __forceinline__ unsigned int cvtpk(float a, float b) {
  unsigned int r;
  asm("v_cvt_pk_bf16_f32 %0, %1, %2" : "=v"(r) : "v"(a), "v"(b));
  return r;
}

// Pack 8 f32 -> 8 bf16 (one 16B store) via 4 packed converts.
__device__ __forceinline__ void cvt_store8(unsigned short* p, float4 a, float4 b) {
  *reinterpret_cast<uint4*>(p) =
      make_uint4(cvtpk(a.x, a.y), cvtpk(a.z, a.w), cvtpk(b.x, b.y), cvtpk(b.z, b.w));
}

// Tile GEMM from LDS with 1-deep register prefetch of next-kt A and B fragments.
template <int MT, int KT, int NTW>
__device__ __forceinline__ void gemm_tile(const unsigned short* A, const int lda,
                                          const unsigned short* Wf,
                                          f32x4 (&acc)[MT][NTW], const int lane) {
  const int ar = lane & 15;
  const int ak = (lane >> 4) << 3;
  bf16x8 bcur[NTW], acur[MT];
#pragma unroll
  for (int n = 0; n < NTW; ++n)
    bcur[n] = *reinterpret_cast<const bf16x8*>(&Wf[(size_t)(n * KT) * 512 + lane * 8]);
#pragma unroll
  for (int m = 0; m < MT; ++m)
    acur[m] = *reinterpret_cast<const bf16x8*>(&A[(m * 16 + ar) * lda + ak]);
#pragma unroll
  for (int kt = 0; kt < KT; ++kt) {
    bf16x8 bnxt[NTW], anxt[MT];
    if (kt + 1 < KT) {
#pragma unroll
      for (int n = 0; n < NTW; ++n)
        bnxt[n] = *reinterpret_cast<const bf16x8*>(
            &Wf[(size_t)(n * KT + kt + 1) * 512 + lane * 8]);
#pragma unroll
      for (int m = 0; m < MT; ++m)
        anxt[m] = *reinterpret_cast<const bf16x8*>(
            &A[(m * 16 + ar) * lda + (kt + 1) * 32 + ak]);
    }
#pragma unroll
    for (int n = 0; n < NTW; ++n)
#pragma unroll
      for (int m = 0; m < MT; ++m)
        acc[m][n] = __builtin_amdgcn_mfma_f32_16x16x32_bf16(acur[m], bcur[n], acc[m][n], 0, 0, 0);
    if (kt + 1 < KT) {
#pragma unroll
      for (int n = 0; n < NTW; ++n) bcur[n] = bnxt[n];
#pragma unroll
      for (int m = 0; m < MT; ++m) acur[m] = anxt[m];
    }
  }
}

// Convert all six weight matrices into MFMA B-fragment order (bf16).
__global__ void prep_weights(const float* __restrict__ mW1, const float* __restrict__ mW2,
                             const float* __restrict__ mW3, const float* __restrict__ uW1,
                             const float* __restrict__ uW2, const float* __restrict__ uW3,
                             unsigned short* __restrict__ wf) {
  const int f = blockIdx.x;
  const int lane = threadIdx.x;
  const float* W; int NC, KT, fl, base;
  if (f < 160)      { W = mW1; NC = 256; KT = 10; fl = f;       base = OF_MW1; }
  else if (f < 288) { W = mW2; NC = 256; KT = 8;  fl = f - 160; base = OF_MW2; }
  else if (f < 352) { W = mW3; NC = 128; KT = 8;  fl = f - 288; base = OF_MW3; }
  else if (f < 544) { W = uW1; NC = 256; KT = 12; fl = f - 352; base = OF_UW1; }
  else if (f < 672) { W = uW2; NC = 256; KT = 8;  fl = f - 544; base = OF_UW2; }
  else              { W = uW3; NC = 128; KT = 8;  fl = f - 672; base = OF_UW3; }
  const int n_t = fl / KT;
  const int k_t = fl % KT;
  const int col = n_t * 16 + (lane & 15);
  const int krow = k_t * 32 + ((lane >> 4) << 3);
  unsigned short* dst = wf + base + (size_t)fl * 512 + lane * 8;
#pragma unroll
  for (int e = 0; e < 8; ++e) dst[e] = f2bf(W[(size_t)(krow + e) * NC + col]);
}

// One launch: bf16 node table + (optional) bf16 edge table + CSR bucket fill.
__global__ void prep_all(const float* __restrict__ ns, unsigned short* __restrict__ nsb,
                         const float* __restrict__ edg, unsigned short* __restrict__ eb,
                         const int* __restrict__ verts, int* __restrict__ cnt,
                         int* __restrict__ eidx, const int csr_base) {
  const int b = blockIdx.x;
  if (b < 4096) {
    const size_t i = ((size_t)b * 256 + threadIdx.x) * 8;
    const float4* s = reinterpret_cast<const float4*>(ns + i);
    cvt_store8(&nsb[i], s[0], s[1]);
  } else if (b < csr_base) {
    const size_t i = ((size_t)(b - 4096) * 256 + threadIdx.x) * 8;
    const float4* s = reinterpret_cast<const float4*>(edg + i);
    cvt_store8(&eb[i], s[0], s[1]);
  } else {
    const int k = (b - csr_base) * 256 + threadIdx.x;
    const int v = verts[k];
    const int slot = atomicAdd(&cnt[v], 1);
    if (slot < 64) eidx[(size_t)v * 64 + slot] = k >> 1;  // message row = edge id
  }
}

// Message MLP — round-12 champion structure: 64 edges/block, 4 waves (1M x 4N),
// row-major [64][328] LDS, 3 blocks/CU, merged one-barrier staging, direct
// accumulator->global layer-3 epilogue.
// MODE: 0 = atomic fallback (f32 sources), 1 = CSR + f32 edges, 2 = CSR + bf16 edges.
template <int MODE>
__global__ __launch_bounds__(256, 3) void msg_kernel(
    const float* __restrict__ ns, const unsigned short* __restrict__ nsb,
    const float* __restrict__ edg, const unsigned short* __restrict__ eb,
    const int* __restrict__ verts, const unsigned short* __restrict__ wf,
    const float* __restrict__ mb1, const float* __restrict__ mb2,
    const float* __restrict__ mb3, float* __restrict__ summed,
    unsigned short* __restrict__ msgs) {
  extern __shared__ unsigned short smem[];
  unsigned short* Xs = smem;  // [64][328] bf16; X cols 0..319, then H 0..255

  const int tid = threadIdx.x;
  const int lane = tid & 63;
  const int w = tid >> 6;
  const int e0 = blockIdx.x * 64;

  // Merged staging: [node_i | node_j | edge] -> Xs, ONE barrier.
  {
    const int r = tid >> 4;
    const int c = (tid & 15) * 8;
#pragma unroll
    for (int p = 0; p < 4; ++p) {
      const int row = p * 16 + r;
      const int2 vv = *reinterpret_cast<const int2*>(&verts[(size_t)(e0 + row) * 2]);
      if constexpr (MODE == 0) {
        const float4* s0 = reinterpret_cast<const float4*>(ns + (size_t)vv.x * 128 + c);
        cvt_store8(&Xs[row * 328 + c], s0[0], s0[1]);
        const float4* s1 = reinterpret_cast<const float4*>(ns + (size_t)vv.y * 128 + c);
        cvt_store8(&Xs[row * 328 + 128 + c], s1[0], s1[1]);
      } else {
        *reinterpret_cast<bf16x8*>(&Xs[row * 328 + c]) =
            *reinterpret_cast<const bf16x8*>(&nsb[(size_t)vv.x * 128 + c]);
        *reinterpret_cast<bf16x8*>(&Xs[row * 328 + 128 + c]) =
            *reinterpret_cast<const bf16x8*>(&nsb[(size_t)vv.y * 128 + c]);
      }
    }
#pragma unroll
    for (int i = tid; i < 512; i += 256) {
      const int row = i >> 3;
      const int cc = (i & 7) * 8;
      if constexpr (MODE == 2) {
        *reinterpret_cast<bf16x8*>(&Xs[row * 328 + 256 + cc]) =
            *reinterpret_cast<const bf16x8*>(&eb[(size_t)(e0 + row) * 64 + cc]);
      } else {
        const float4* s2 = reinterpret_cast<const float4*>(edg + (size_t)(e0 + row) * 64 + cc);
        cvt_store8(&Xs[row * 328 + 256 + cc], s2[0], s2[1]);
      }
    }
  }
  __syncthreads();

  const int cw = lane & 15;
  const int rq = (lane >> 4) * 4;

  // Layer 1: 320 -> 256, relu. Each wave: 64 output cols. H written back into Xs.
  {
    f32x4 acc[4][4];
#pragma unroll
    for (int m = 0; m < 4; ++m)
#pragma unroll
      for (int n = 0; n < 4; ++n)
#pragma unroll
        for (int i = 0; i < 4; ++i) acc[m][n][i] = 0.0f;
    gemm_tile<4, 10, 4>(Xs, 328, wf + OF_MW1 + (size_t)(w * 4) * 10 * 512, acc, lane);
    __syncthreads();
#pragma unroll
    for (int n = 0; n < 4; ++n) {
      const int col = w * 64 + n * 16 + cw;
      const float bias = mb1[col];
#pragma unroll
      for (int m = 0; m < 4; ++m)
#pragma unroll
        for (int q = 0; q < 4; ++q) {
          const int row = m * 16 + rq + q;
          Xs[row * 328 + col] = f2bf(fmaxf(acc[m][n][q] + bias, 0.0f));
        }
    }
  }
  __syncthreads();

  // Layer 2: 256 -> 256, relu, in-place on Xs.
  {
    f32x4 acc[4][4];
#pragma unroll
    for (int m = 0; m < 4; ++m)
#pragma unroll
      for (int n = 0; n < 4; ++n)
#pragma unroll
        for (int i = 0; i < 4; ++i) acc[m][n][i] = 0.0f;
    gemm_tile<4, 8, 4>(Xs, 328, wf + OF_MW2 + (size_t)(w * 4) * 8 * 512, acc, lane);
    __syncthreads();
#pragma unroll
    for (int n = 0; n < 4; ++n) {
      const int col = w * 64 + n * 16 + cw;
      const float bias = mb2[col];
#pragma unroll
      for (int m = 0; m < 4; ++m)
#pragma unroll
        for (int q = 0; q < 4; ++q) {
          const int row = m * 16 + rq + q;
          Xs[row * 328 + col] = f2bf(fmaxf(acc[m][n][q] + bias, 0.0f));
        }
    }
  }
  __syncthreads();

  // Layer 3: 256 -> 128, straight from accumulators to output (no LDS, no barrier).
  {
    f32x4 acc[4][2];
#pragma unroll
    for (int m = 0; m < 4; ++m)
#pragma unroll
      for (int n = 0; n < 2; ++n)
#pragma unroll
        for (int i = 0; i < 4; ++i) acc[m][n][i] = 0.0f;
    gemm_tile<4, 8, 2>(Xs, 328, wf + OF_MW3 + (size_t)(w * 2) * 8 * 512, acc, lane);

    if constexpr (MODE == 0) {
#pragma unroll
      for (int n = 0; n < 2; ++n) {
        const int col = w * 32 + n * 16 + cw;
        const float bias = mb3[col];
#pragma unroll
        for (int m = 0; m < 4; ++m)
#pragma unroll
          for (int q = 0; q < 4; ++q) {
            const int row = m * 16 + rq + q;
            const int2 vv = *reinterpret_cast<const int2*>(&verts[(size_t)(e0 + row) * 2]);
            const float v = acc[m][n][q] + bias;
            unsafeAtomicAdd(&summed[(size_t)vv.x * 128 + col], v);
            unsafeAtomicAdd(&summed[(size_t)vv.y * 128 + col], v);
          }
      }
    } else {
#pragma unroll
      for (int n = 0; n < 2; ++n) {
        const int col = w * 32 + n * 16 + cw;
        const float bias = mb3[col];
#pragma unroll
        for (int m = 0; m < 4; ++m)
#pragma unroll
          for (int q = 0; q < 4; ++q) {
            const int row = m * 16 + rq + q;
            msgs[(size_t)(e0 + row) * 128 + col] = f2bf(acc[m][n][q] + bias);
          }
      }
    }
  }
}

// Update MLP: 32 nodes per workgroup, 2 waves, NTW=8, single LDS buffer.
// LDS = 32*392*2 = 25088 B -> 6 blocks/CU. attention[n] = ns[n] - ns[n^2048].
template <bool GATHER>
__global__ __launch_bounds__(128, 3) void upd_kernel(
    const float* __restrict__ ns, const float* __restrict__ summed,
    const unsigned short* __restrict__ msgs, const int* __restrict__ cnt,
    const int* __restrict__ eidx, const unsigned short* __restrict__ wf,
    const float* __restrict__ ub1, const float* __restrict__ ub2,
    const float* __restrict__ ub3, float* __restrict__ out) {
  extern __shared__ unsigned short smem[];
  unsigned short* Xs = smem;  // [32][392]; X cols 0..383, then H 0..255

  const int tid = threadIdx.x;
  const int lane = tid & 63;
  const int w = tid >> 6;
  const int n0 = blockIdx.x * 32;

  // Phase 1: node | attention -> Xs; summed read (fallback) or eidx staging (CSR).
  for (int i = tid; i < 512; i += 128) {
    const int row = i >> 4;
    const int c = (i & 15) * 8;
    const int n = n0 + row;
    const float4* sA = reinterpret_cast<const float4*>(ns + (size_t)n * 128 + c);
    const float4 a0 = sA[0], a1 = sA[1];
    cvt_store8(&Xs[row * 392 + c], a0, a1);
    if constexpr (!GATHER) {
      const float4* sS = reinterpret_cast<const float4*>(summed + (size_t)n * 128 + c);
      cvt_store8(&Xs[row * 392 + 128 + c], sS[0], sS[1]);
    }
    const float4* sP = reinterpret_cast<const float4*>(ns + (size_t)(n ^ 2048) * 128 + c);
    const float4 p0 = sP[0], p1 = sP[1];
    float4 d0, d1;
    d0.x = a0.x - p0.x; d0.y = a0.y - p0.y; d0.z = a0.z - p0.z; d0.w = a0.w - p0.w;
    d1.x = a1.x - p1.x; d1.y = a1.y - p1.y; d1.z = a1.z - p1.z; d1.w = a1.w - p1.w;
    cvt_store8(&Xs[row * 392 + 256 + c], d0, d1);
  }

  if constexpr (GATHER) {
    // Stage this tile's eidx lists into Xs cols 128..255 (64 ints per row).
    for (int i = tid; i < 512; i += 128) {
      const int row = i >> 4;
      const int q4 = i & 15;
      reinterpret_cast<int4*>(&Xs[row * 392 + 128])[q4] =
          reinterpret_cast<const int4*>(&eidx[(size_t)(n0 + row) * 64])[q4];
    }
    __syncthreads();

    // 4 threads per node, 32 cols each; fp32 accumulate in registers.
    const int nl = tid >> 2;
    const int part = tid & 3;
    const int cn = min(cnt[n0 + nl], 64);
    const int* el = reinterpret_cast<const int*>(&Xs[nl * 392 + 128]);
    float acc[32];
#pragma unroll
    for (int k = 0; k < 32; ++k) acc[k] = 0.0f;
    for (int j = 0; j < cn; ++j) {
      const int e = el[j];
      const bf16x8* mp = reinterpret_cast<const bf16x8*>(&msgs[(size_t)e * 128 + part * 32]);
#pragma unroll
      for (int t = 0; t < 4; ++t) {
        const bf16x8 v = mp[t];
#pragma unroll
        for (int k = 0; k < 8; ++k) acc[t * 8 + k] += bf2f(v[k]);
      }
    }
    __syncthreads();  // all eidx LDS reads done before overwrite
#pragma unroll
    for (int t = 0; t < 4; ++t) {
      *reinterpret_cast<uint4*>(&Xs[nl * 392 + 128 + part * 32 + t * 8]) =
          make_uint4(cvtpk(acc[t * 8 + 0], acc[t * 8 + 1]), cvtpk(acc[t * 8 + 2], acc[t * 8 + 3]),
                     cvtpk(acc[t * 8 + 4], acc[t * 8 + 5]), cvtpk(acc[t * 8 + 6], acc[t * 8 + 7]));
    }
  }
  __syncthreads();

  const int cw = lane & 15;
  const int rq = (lane >> 4) * 4;

  // Layer 1: 384 -> 256, relu. Each wave: 128 output cols. H back into Xs.
  {
    f32x4 acc[2][8];
#pragma unroll
    for (int m = 0; m < 2; ++m)
#pragma unroll
      for (int n = 0; n < 8; ++n)
#pragma unroll
        for (int i = 0; i < 4; ++i) acc[m][n][i] = 0.0f;
    gemm_tile<2, 12, 8>(Xs, 392, wf + OF_UW1 + (size_t)(w * 8) * 12 * 512, acc, lane);
    __syncthreads();
#pragma unroll
    for (int n = 0; n < 8; ++n) {
      const int col = w * 128 + n * 16 + cw;
      const float bias = ub1[col];
#pragma unroll
      for (int m = 0; m < 2; ++m)
#pragma unroll
        for (int q = 0; q < 4; ++q) {
          const int row = m * 16 + rq + q;
          Xs[row * 392 + col] = f2bf(fmaxf(acc[m][n][q] + bias, 0.0f));
        }
    }
  }
  __syncthreads();

  // Layer 2: 256 -> 256, relu, in-place on Xs.
  {
    f32x4 acc[2][8];
#pragma unroll
    for (int m = 0; m < 2; ++m)
#pragma unroll
      for (int n = 0; n < 8; ++n)
#pragma unroll
        for (int i = 0; i < 4; ++i) acc[m][n][i] = 0.0f;
    gemm_tile<2, 8, 8>(Xs, 392, wf + OF_UW2 + (size_t)(w * 8) * 8 * 512, acc, lane);
    __syncthreads();
#pragma unroll
    for (int n = 0; n < 8; ++n) {
      const int col = w * 128 + n * 16 + cw;
      const float bias = ub2[col];
#pragma unroll
      for (int m = 0; m < 2; ++m)
#pragma unroll
        for (int q = 0; q < 4; ++q) {
          const int row = m * 16 + rq + q;
          Xs[row * 392 + col] = f2bf(fmaxf(acc[m][n][q] + bias, 0.0f));
        }
    }
  }
  __syncthreads();

  // Layer 3: 256 -> 128 -> out (fp32). Each wave: 64 output cols.
  {
    f32x4 acc[2][4];
#pragma unroll
    for (int m = 0; m < 2; ++m)
#pragma unroll
      for (int n = 0; n < 4; ++n)
#pragma unroll
        for (int i = 0; i < 4; ++i) acc[m][n][i] = 0.0f;
    gemm_tile<2, 8, 4>(Xs, 392, wf + OF_UW3 + (size_t)(w * 4) * 8 * 512, acc, lane);
#pragma unroll
    for (int n = 0; n < 4; ++n) {
      const int col = w * 64 + n * 16 + cw;
      const float bias = ub3[col];
#pragma unroll
      for (int m = 0; m < 2; ++m)
#pragma unroll
        for (int q = 0; q < 4; ++q) {
          const int row = m * 16 + rq + q;
          out[(size_t)(n0 + row) * 128 + col] = acc[m][n][q] + bias;
        }
    }
  }
}

extern "C" void kernel_launch(void* const* d_in, const int* in_sizes, int n_in,
                              void* d_out, int out_size, void* d_ws, size_t ws_size,
                              hipStream_t stream) {
  const float* ns   = (const float*)d_in[0];
  const float* edg  = (const float*)d_in[1];
  const int* verts  = (const int*)d_in[2];
  const float* mW1  = (const float*)d_in[3];
  const float* mb1  = (const float*)d_in[4];
  const float* mW2  = (const float*)d_in[5];
  const float* mb2  = (const float*)d_in[6];
  const float* mW3  = (const float*)d_in[7];
  const float* mb3  = (const float*)d_in[8];
  const float* uW1  = (const float*)d_in[9];
  const float* ub1  = (const float*)d_in[10];
  const float* uW2  = (const float*)d_in[11];
  const float* ub2  = (const float*)d_in[12];
  const float* uW3  = (const float*)d_in[13];
  const float* ub3  = (const float*)d_in[14];
  float* out = (float*)d_out;

  const int msg_lds = 64 * 328 * 2;  // 41984 B -> 3 blocks/CU
  const int upd_lds = 32 * 392 * 2;  // 25088 B -> 6 blocks/CU

  if (ws_size >= WS_NEED) {
    unsigned short* msgs = (unsigned short*)d_ws;
    unsigned short* nsb  = (unsigned short*)((char*)d_ws + WS_NSB_OFF);
    int* eidx = (int*)((char*)d_ws + WS_EIDX_OFF);
    int* cnt  = (int*)((char*)d_ws + WS_CNT_OFF);
    unsigned short* wf = (unsigned short*)((char*)d_ws + WS_WF_OFF);
    const bool has_eb = ws_size >= WS_NEED2;
    unsigned short* eb = has_eb ? (unsigned short*)((char*)d_ws + WS_EB_OFF) : nullptr;
    const int csr_base = has_eb ? 20480 : 4096;

    (void)hipMemsetAsync(cnt, 0, WS_CNT_BYTES, stream);
    prep_weights<<<736, 64, 0, stream>>>(mW1, mW2, mW3, uW1, uW2, uW3, wf);
    prep_all<<<csr_base + 4096, 256, 0, stream>>>(ns, nsb, edg, eb, verts, cnt, eidx, csr_base);
    if (has_eb)
      msg_kernel<2><<<NEDGES / 64, 256, msg_lds, stream>>>(
          ns, nsb, edg, eb, verts, wf, mb1, mb2, mb3, nullptr, msgs);
    else
      msg_kernel<1><<<NEDGES / 64, 256, msg_lds, stream>>>(
          ns, nsb, edg, nullptr, verts, wf, mb1, mb2, mb3, nullptr, msgs);
    upd_kernel<true><<<NNODES / 32, 128, upd_lds, stream>>>(
        ns, nullptr, msgs, cnt, eidx, wf, ub1, ub2, ub3, out);
  } else {
    float* summed = (float*)d_ws;
    unsigned short* wf = (unsigned short*)((char*)d_ws + WS_SUMMED_BYTES);

    (void)hipMemsetAsync(summed, 0, WS_SUMMED_BYTES, stream);
    prep_weights<<<736, 64, 0, stream>>>(mW1, mW2, mW3, uW1, uW2, uW3, wf);
    msg_kernel<0><<<NEDGES / 64, 256, msg_lds, stream>>>(
        ns, nullptr, edg, nullptr, verts, wf, mb1, mb2, mb3, summed, nullptr);
    upd_kernel<false><<<NNODES / 32, 128, upd_lds, stream>>>(
        ns, summed, nullptr, nullptr, nullptr, wf, ub1, ub2, ub3, out);
  }
}

// Round 16
// 473.325 us; speedup vs baseline: 1.2784x; 1.0442x over previous
//
#include <hip/hip_runtime.h>

// Problem constants
#define NNODES 65536
#define NEDGES 524288

typedef short bf16x8 __attribute__((ext_vector_type(8)));
typedef float f32x4 __attribute__((ext_vector_type(4)));

// Packed-weight fragment offsets (in bf16 elements) within the weight region.
// Fragment layout per matrix (K x NC): [n_tile][k_tile][lane][8], 512 bf16 per fragment.
#define OF_MW1 0        // 320x256: KT=10, NT=16 -> 81920
#define OF_MW2 81920    // 256x256: KT=8,  NT=16 -> 65536
#define OF_MW3 147456   // 256x128: KT=8,  NT=8  -> 32768
#define OF_UW1 180224   // 384x256: KT=12, NT=16 -> 98304
#define OF_UW2 278528   // 256x256: KT=8,  NT=16 -> 65536
#define OF_UW3 344064   // 256x128: KT=8,  NT=8  -> 32768
#define WF_BYTES (376832 * 2)

// Big-workspace layout (CSR path)
#define WS_MSGS_BYTES ((size_t)NEDGES * 128 * 2)          // 134217728 (bf16)
#define WS_NSB_OFF    WS_MSGS_BYTES
#define WS_NSB_BYTES  ((size_t)NNODES * 128 * 2)          // 16777216 (bf16 node table)
#define WS_EIDX_OFF   (WS_NSB_OFF + WS_NSB_BYTES)
#define WS_EIDX_BYTES ((size_t)NNODES * 64 * 4)           // 16777216
#define WS_CNT_OFF    (WS_EIDX_OFF + WS_EIDX_BYTES)
#define WS_CNT_BYTES  ((size_t)NNODES * 4)                // 262144
#define WS_WF_OFF     (WS_CNT_OFF + WS_CNT_BYTES)
#define WS_NEED       (WS_WF_OFF + WF_BYTES)

// Fallback layout (atomic path)
#define WS_SUMMED_BYTES ((size_t)NNODES * 128 * 4)

__device__ __forceinline__ unsigned short f2bf(float x) {
  unsigned int u = __float_as_uint(x);
  return (unsigned short)((u + 0x7FFFu + ((u >> 16) & 1u)) >> 16);  // RNE
}

__device__ __forceinline__ float bf2f(short s) {
  return __uint_as_float((unsigned int)(unsigned short)s << 16);
}

// v_cvt_pk_bf16_f32 (RNE): result.lo16 = bf16(a), result.hi16 = bf16(b).
__device__ __forceinline__ unsigned int cvtpk(float a, float b) {
  unsigned int r;
  asm("v_cvt_pk_bf16_f32 %0, %1, %2" : "=v"(r) : "v"(a), "v"(b));
  return r;
}

// Pack 8 f32 -> 8 bf16 (one 16B store) via 4 packed converts.
__device__ __forceinline__ void cvt_store8(unsigned short* p, float4 a, float4 b) {
  *reinterpret_cast<uint4*>(p) =
      make_uint4(cvtpk(a.x, a.y), cvtpk(a.z, a.w), cvtpk(b.x, b.y), cvtpk(b.z, b.w));
}

// Tile GEMM from LDS with 1-deep register prefetch of next-kt A and B fragments.
template <int MT, int KT, int NTW>
__device__ __forceinline__ void gemm_tile(const unsigned short* A, const int lda,
                                          const unsigned short* Wf,
                                          f32x4 (&acc)[MT][NTW], const int lane) {
  const int ar = lane & 15;
  const int ak = (lane >> 4) << 3;
  bf16x8 bcur[NTW], acur[MT];
#pragma unroll
  for (int n = 0; n < NTW; ++n)
    bcur[n] = *reinterpret_cast<const bf16x8*>(&Wf[(size_t)(n * KT) * 512 + lane * 8]);
#pragma unroll
  for (int m = 0; m < MT; ++m)
    acur[m] = *reinterpret_cast<const bf16x8*>(&A[(m * 16 + ar) * lda + ak]);
#pragma unroll
  for (int kt = 0; kt < KT; ++kt) {
    bf16x8 bnxt[NTW], anxt[MT];
    if (kt + 1 < KT) {
#pragma unroll
      for (int n = 0; n < NTW; ++n)
        bnxt[n] = *reinterpret_cast<const bf16x8*>(
            &Wf[(size_t)(n * KT + kt + 1) * 512 + lane * 8]);
#pragma unroll
      for (int m = 0; m < MT; ++m)
        anxt[m] = *reinterpret_cast<const bf16x8*>(
            &A[(m * 16 + ar) * lda + (kt + 1) * 32 + ak]);
    }
#pragma unroll
    for (int n = 0; n < NTW; ++n)
#pragma unroll
      for (int m = 0; m < MT; ++m)
        acc[m][n] = __builtin_amdgcn_mfma_f32_16x16x32_bf16(acur[m], bcur[n], acc[m][n], 0, 0, 0);
    if (kt + 1 < KT) {
#pragma unroll
      for (int n = 0; n < NTW; ++n) bcur[n] = bnxt[n];
#pragma unroll
      for (int m = 0; m < MT; ++m) acur[m] = anxt[m];
    }
  }
}

// Convert all six weight matrices into MFMA B-fragment order (bf16).
__global__ void prep_weights(const float* __restrict__ mW1, const float* __restrict__ mW2,
                             const float* __restrict__ mW3, const float* __restrict__ uW1,
                             const float* __restrict__ uW2, const float* __restrict__ uW3,
                             unsigned short* __restrict__ wf) {
  const int f = blockIdx.x;
  const int lane = threadIdx.x;
  const float* W; int NC, KT, fl, base;
  if (f < 160)      { W = mW1; NC = 256; KT = 10; fl = f;       base = OF_MW1; }
  else if (f < 288) { W = mW2; NC = 256; KT = 8;  fl = f - 160; base = OF_MW2; }
  else if (f < 352) { W = mW3; NC = 128; KT = 8;  fl = f - 288; base = OF_MW3; }
  else if (f < 544) { W = uW1; NC = 256; KT = 12; fl = f - 352; base = OF_UW1; }
  else if (f < 672) { W = uW2; NC = 256; KT = 8;  fl = f - 544; base = OF_UW2; }
  else              { W = uW3; NC = 128; KT = 8;  fl = f - 672; base = OF_UW3; }
  const int n_t = fl / KT;
  const int k_t = fl % KT;
  const int col = n_t * 16 + (lane & 15);
  const int krow = k_t * 32 + ((lane >> 4) << 3);
  unsigned short* dst = wf + base + (size_t)fl * 512 + lane * 8;
#pragma unroll
  for (int e = 0; e < 8; ++e) dst[e] = f2bf(W[(size_t)(krow + e) * NC + col]);
}

// One launch: bf16 node table + CSR bucket fill.
__global__ void prep_all(const float* __restrict__ ns, unsigned short* __restrict__ nsb,
                         const int* __restrict__ verts, int* __restrict__ cnt,
                         int* __restrict__ eidx) {
  const int b = blockIdx.x;
  if (b < 4096) {
    const size_t i = ((size_t)b * 256 + threadIdx.x) * 8;
    const float4* s = reinterpret_cast<const float4*>(ns + i);
    cvt_store8(&nsb[i], s[0], s[1]);
  } else {
    const int k = (b - 4096) * 256 + threadIdx.x;
    const int v = verts[k];
    const int slot = atomicAdd(&cnt[v], 1);
    if (slot < 64) eidx[(size_t)v * 64 + slot] = k >> 1;  // message row = edge id
  }
}

// Message MLP — champion structure: 64 edges/block, 4 waves (1M x 4N),
// row-major [64][328] LDS, 3 blocks/CU, merged one-barrier staging (bf16 node
// table gather + in-staging edge cvt), direct accumulator->global layer-3.
// ATOMIC=true: f32 sources + scatter-add fallback.
template <bool ATOMIC>
__global__ __launch_bounds__(256, 3) void msg_kernel(
    const float* __restrict__ ns, const unsigned short* __restrict__ nsb,
    const float* __restrict__ edg, const int* __restrict__ verts,
    const unsigned short* __restrict__ wf, const float* __restrict__ mb1,
    const float* __restrict__ mb2, const float* __restrict__ mb3,
    float* __restrict__ summed, unsigned short* __restrict__ msgs) {
  extern __shared__ unsigned short smem[];
  unsigned short* Xs = smem;  // [64][328] bf16; X cols 0..319, then H 0..255

  const int tid = threadIdx.x;
  const int lane = tid & 63;
  const int w = tid >> 6;
  const int e0 = blockIdx.x * 64;

  // Merged staging: [node_i | node_j | edge] -> Xs, ONE barrier.
  {
    const int r = tid >> 4;
    const int c = (tid & 15) * 8;
#pragma unroll
    for (int p = 0; p < 4; ++p) {
      const int row = p * 16 + r;
      const int2 vv = *reinterpret_cast<const int2*>(&verts[(size_t)(e0 + row) * 2]);
      if constexpr (ATOMIC) {
        const float4* s0 = reinterpret_cast<const float4*>(ns + (size_t)vv.x * 128 + c);
        cvt_store8(&Xs[row * 328 + c], s0[0], s0[1]);
        const float4* s1 = reinterpret_cast<const float4*>(ns + (size_t)vv.y * 128 + c);
        cvt_store8(&Xs[row * 328 + 128 + c], s1[0], s1[1]);
      } else {
        *reinterpret_cast<bf16x8*>(&Xs[row * 328 + c]) =
            *reinterpret_cast<const bf16x8*>(&nsb[(size_t)vv.x * 128 + c]);
        *reinterpret_cast<bf16x8*>(&Xs[row * 328 + 128 + c]) =
            *reinterpret_cast<const bf16x8*>(&nsb[(size_t)vv.y * 128 + c]);
      }
    }
#pragma unroll
    for (int i = tid; i < 512; i += 256) {
      const int row = i >> 3;
      const int cc = (i & 7) * 8;
      const float4* s2 = reinterpret_cast<const float4*>(edg + (size_t)(e0 + row) * 64 + cc);
      cvt_store8(&Xs[row * 328 + 256 + cc], s2[0], s2[1]);
    }
  }
  __syncthreads();

  const int cw = lane & 15;
  const int rq = (lane >> 4) * 4;

  // Layer 1: 320 -> 256, relu. Each wave: 64 output cols. H written back into Xs.
  {
    f32x4 acc[4][4];
#pragma unroll
    for (int m = 0; m < 4; ++m)
#pragma unroll
      for (int n = 0; n < 4; ++n)
#pragma unroll
        for (int i = 0; i < 4; ++i) acc[m][n][i] = 0.0f;
    gemm_tile<4, 10, 4>(Xs, 328, wf + OF_MW1 + (size_t)(w * 4) * 10 * 512, acc, lane);
    __syncthreads();
#pragma unroll
    for (int n = 0; n < 4; ++n) {
      const int col = w * 64 + n * 16 + cw;
      const float bias = mb1[col];
#pragma unroll
      for (int m = 0; m < 4; ++m)
#pragma unroll
        for (int q = 0; q < 4; ++q) {
          const int row = m * 16 + rq + q;
          Xs[row * 328 + col] = f2bf(fmaxf(acc[m][n][q] + bias, 0.0f));
        }
    }
  }
  __syncthreads();

  // Layer 2: 256 -> 256, relu, in-place on Xs.
  {
    f32x4 acc[4][4];
#pragma unroll
    for (int m = 0; m < 4; ++m)
#pragma unroll
      for (int n = 0; n < 4; ++n)
#pragma unroll
        for (int i = 0; i < 4; ++i) acc[m][n][i] = 0.0f;
    gemm_tile<4, 8, 4>(Xs, 328, wf + OF_MW2 + (size_t)(w * 4) * 8 * 512, acc, lane);
    __syncthreads();
#pragma unroll
    for (int n = 0; n < 4; ++n) {
      const int col = w * 64 + n * 16 + cw;
      const float bias = mb2[col];
#pragma unroll
      for (int m = 0; m < 4; ++m)
#pragma unroll
        for (int q = 0; q < 4; ++q) {
          const int row = m * 16 + rq + q;
          Xs[row * 328 + col] = f2bf(fmaxf(acc[m][n][q] + bias, 0.0f));
        }
    }
  }
  __syncthreads();

  // Layer 3: 256 -> 128, straight from accumulators to output (no LDS, no barrier).
  {
    f32x4 acc[4][2];
#pragma unroll
    for (int m = 0; m < 4; ++m)
#pragma unroll
      for (int n = 0; n < 2; ++n)
#pragma unroll
        for (int i = 0; i < 4; ++i) acc[m][n][i] = 0.0f;
    gemm_tile<4, 8, 2>(Xs, 328, wf + OF_MW3 + (size_t)(w * 2) * 8 * 512, acc, lane);

    if constexpr (ATOMIC) {
#pragma unroll
      for (int n = 0; n < 2; ++n) {
        const int col = w * 32 + n * 16 + cw;
        const float bias = mb3[col];
#pragma unroll
        for (int m = 0; m < 4; ++m)
#pragma unroll
          for (int q = 0; q < 4; ++q) {
            const int row = m * 16 + rq + q;
            const int2 vv = *reinterpret_cast<const int2*>(&verts[(size_t)(e0 + row) * 2]);
            const float v = acc[m][n][q] + bias;
            unsafeAtomicAdd(&summed[(size_t)vv.x * 128 + col], v);
            unsafeAtomicAdd(&summed[(size_t)vv.y * 128 + col], v);
          }
      }
    } else {
#pragma unroll
      for (int n = 0; n < 2; ++n) {
        const int col = w * 32 + n * 16 + cw;
        const float bias = mb3[col];
#pragma unroll
        for (int m = 0; m < 4; ++m)
#pragma unroll
          for (int q = 0; q < 4; ++q) {
            const int row = m * 16 + rq + q;
            msgs[(size_t)(e0 + row) * 128 + col] = f2bf(acc[m][n][q] + bias);
          }
      }
    }
  }
}

// Update MLP: 32 nodes per workgroup, 2 waves, NTW=8, single LDS buffer.
// LDS = 32*392*2 = 25088 B -> 6 blocks/CU. attention[n] = ns[n] - ns[n^2048].
template <bool GATHER>
__global__ __launch_bounds__(128, 3) void upd_kernel(
    const float* __restrict__ ns, const float* __restrict__ summed,
    const unsigned short* __restrict__ msgs, const int* __restrict__ cnt,
    const int* __restrict__ eidx, const unsigned short* __restrict__ wf,
    const float* __restrict__ ub1, const float* __restrict__ ub2,
    const float* __restrict__ ub3, float* __restrict__ out) {
  extern __shared__ unsigned short smem[];
  unsigned short* Xs = smem;  // [32][392]; X cols 0..383, then H 0..255

  const int tid = threadIdx.x;
  const int lane = tid & 63;
  const int w = tid >> 6;
  const int n0 = blockIdx.x * 32;

  // Phase 1: node | attention -> Xs; summed read (fallback) or eidx staging (CSR).
  for (int i = tid; i < 512; i += 128) {
    const int row = i >> 4;
    const int c = (i & 15) * 8;
    const int n = n0 + row;
    const float4* sA = reinterpret_cast<const float4*>(ns + (size_t)n * 128 + c);
    const float4 a0 = sA[0], a1 = sA[1];
    cvt_store8(&Xs[row * 392 + c], a0, a1);
    if constexpr (!GATHER) {
      const float4* sS = reinterpret_cast<const float4*>(summed + (size_t)n * 128 + c);
      cvt_store8(&Xs[row * 392 + 128 + c], sS[0], sS[1]);
    }
    const float4* sP = reinterpret_cast<const float4*>(ns + (size_t)(n ^ 2048) * 128 + c);
    const float4 p0 = sP[0], p1 = sP[1];
    float4 d0, d1;
    d0.x = a0.x - p0.x; d0.y = a0.y - p0.y; d0.z = a0.z - p0.z; d0.w = a0.w - p0.w;
    d1.x = a1.x - p1.x; d1.y = a1.y - p1.y; d1.z = a1.z - p1.z; d1.w = a1.w - p1.w;
    cvt_store8(&Xs[row * 392 + 256 + c], d0, d1);
  }

  if constexpr (GATHER) {
    // Stage this tile's eidx lists into Xs cols 128..255 (64 ints per row).
    for (int i = tid; i < 512; i += 128) {
      const int row = i >> 4;
      const int q4 = i & 15;
      reinterpret_cast<int4*>(&Xs[row * 392 + 128])[q4] =
          reinterpret_cast<const int4*>(&eidx[(size_t)(n0 + row) * 64])[q4];
    }
    __syncthreads();

    // 4 threads per node, 32 cols each; fp32 accumulate in registers.
    const int nl = tid >> 2;
    const int part = tid & 3;
    const int cn = min(cnt[n0 + nl], 64);
    const int* el = reinterpret_cast<const int*>(&Xs[nl * 392 + 128]);
    float acc[32];
#pragma unroll
    for (int k = 0; k < 32; ++k) acc[k] = 0.0f;
    for (int j = 0; j < cn; ++j) {
      const int e = el[j];
      const bf16x8* mp = reinterpret_cast<const bf16x8*>(&msgs[(size_t)e * 128 + part * 32]);
#pragma unroll
      for (int t = 0; t < 4; ++t) {
        const bf16x8 v = mp[t];
#pragma unroll
        for (int k = 0; k < 8; ++k) acc[t * 8 + k] += bf2f(v[k]);
      }
    }
    __syncthreads();  // all eidx LDS reads done before overwrite
#pragma unroll
    for (int t = 0; t < 4; ++t) {
      *reinterpret_cast<uint4*>(&Xs[nl * 392 + 128 + part * 32 + t * 8]) =
          make_uint4(cvtpk(acc[t * 8 + 0], acc[t * 8 + 1]), cvtpk(acc[t * 8 + 2], acc[t * 8 + 3]),
                     cvtpk(acc[t * 8 + 4], acc[t * 8 + 5]), cvtpk(acc[t * 8 + 6], acc[t * 8 + 7]));
    }
  }
  __syncthreads();

  const int cw = lane & 15;
  const int rq = (lane >> 4) * 4;

  // Layer 1: 384 -> 256, relu. Each wave: 128 output cols. H back into Xs.
  {
    f32x4 acc[2][8];
#pragma unroll
    for (int m = 0; m < 2; ++m)
#pragma unroll
      for (int n = 0; n < 8; ++n)
#pragma unroll
        for (int i = 0; i < 4; ++i) acc[m][n][i] = 0.0f;
    gemm_tile<2, 12, 8>(Xs, 392, wf + OF_UW1 + (size_t)(w * 8) * 12 * 512, acc, lane);
    __syncthreads();
#pragma unroll
    for (int n = 0; n < 8; ++n) {
      const int col = w * 128 + n * 16 + cw;
      const float bias = ub1[col];
#pragma unroll
      for (int m = 0; m < 2; ++m)
#pragma unroll
        for (int q = 0; q < 4; ++q) {
          const int row = m * 16 + rq + q;
          Xs[row * 392 + col] = f2bf(fmaxf(acc[m][n][q] + bias, 0.0f));
        }
    }
  }
  __syncthreads();

  // Layer 2: 256 -> 256, relu, in-place on Xs.
  {
    f32x4 acc[2][8];
#pragma unroll
    for (int m = 0; m < 2; ++m)
#pragma unroll
      for (int n = 0; n < 8; ++n)
#pragma unroll
        for (int i = 0; i < 4; ++i) acc[m][n][i] = 0.0f;
    gemm_tile<2, 8, 8>(Xs, 392, wf + OF_UW2 + (size_t)(w * 8) * 8 * 512, acc, lane);
    __syncthreads();
#pragma unroll
    for (int n = 0; n < 8; ++n) {
      const int col = w * 128 + n * 16 + cw;
      const float bias = ub2[col];
#pragma unroll
      for (int m = 0; m < 2; ++m)
#pragma unroll
        for (int q = 0; q < 4; ++q) {
          const int row = m * 16 + rq + q;
          Xs[row * 392 + col] = f2bf(fmaxf(acc[m][n][q] + bias, 0.0f));
        }
    }
  }
  __syncthreads();

  // Layer 3: 256 -> 128 -> out (fp32). Each wave: 64 output cols.
  {
    f32x4 acc[2][4];
#pragma unroll
    for (int m = 0; m < 2; ++m)
#pragma unroll
      for (int n = 0; n < 4; ++n)
#pragma unroll
        for (int i = 0; i < 4; ++i) acc[m][n][i] = 0.0f;
    gemm_tile<2, 8, 4>(Xs, 392, wf + OF_UW3 + (size_t)(w * 4) * 8 * 512, acc, lane);
#pragma unroll
    for (int n = 0; n < 4; ++n) {
      const int col = w * 64 + n * 16 + cw;
      const float bias = ub3[col];
#pragma unroll
      for (int m = 0; m < 2; ++m)
#pragma unroll
        for (int q = 0; q < 4; ++q) {
          const int row = m * 16 + rq + q;
          out[(size_t)(n0 + row) * 128 + col] = acc[m][n][q] + bias;
        }
    }
  }
}

extern "C" void kernel_launch(void* const* d_in, const int* in_sizes, int n_in,
                              void* d_out, int out_size, void* d_ws, size_t ws_size,
                              hipStream_t stream) {
  const float* ns   = (const float*)d_in[0];
  const float* edg  = (const float*)d_in[1];
  const int* verts  = (const int*)d_in[2];
  const float* mW1  = (const float*)d_in[3];
  const float* mb1  = (const float*)d_in[4];
  const float* mW2  = (const float*)d_in[5];
  const float* mb2  = (const float*)d_in[6];
  const float* mW3  = (const float*)d_in[7];
  const float* mb3  = (const float*)d_in[8];
  const float* uW1  = (const float*)d_in[9];
  const float* ub1  = (const float*)d_in[10];
  const float* uW2  = (const float*)d_in[11];
  const float* ub2  = (const float*)d_in[12];
  const float* uW3  = (const float*)d_in[13];
  const float* ub3  = (const float*)d_in[14];
  float* out = (float*)d_out;

  const int msg_lds = 64 * 328 * 2;  // 41984 B -> 3 blocks/CU
  const int upd_lds = 32 * 392 * 2;  // 25088 B -> 6 blocks/CU

  if (ws_size >= WS_NEED) {
    // CSR path: no fp32 scatter-atomics; bf16 node table for the gather.
    unsigned short* msgs = (unsigned short*)d_ws;
    unsigned short* nsb  = (unsigned short*)((char*)d_ws + WS_NSB_OFF);
    int* eidx = (int*)((char*)d_ws + WS_EIDX_OFF);
    int* cnt  = (int*)((char*)d_ws + WS_CNT_OFF);
    unsigned short* wf = (unsigned short*)((char*)d_ws + WS_WF_OFF);

    (void)hipMemsetAsync(cnt, 0, WS_CNT_BYTES, stream);
    prep_weights<<<736, 64, 0, stream>>>(mW1, mW2, mW3, uW1, uW2, uW3, wf);
    prep_all<<<4096 + 4096, 256, 0, stream>>>(ns, nsb, verts, cnt, eidx);
    msg_kernel<false><<<NEDGES / 64, 256, msg_lds, stream>>>(
        ns, nsb, edg, verts, wf, mb1, mb2, mb3, nullptr, msgs);
    upd_kernel<true><<<NNODES / 32, 128, upd_lds, stream>>>(
        ns, nullptr, msgs, cnt, eidx, wf, ub1, ub2, ub3, out);
  } else {
    // Fallback: atomic path.
    float* summed = (float*)d_ws;
    unsigned short* wf = (unsigned short*)((char*)d_ws + WS_SUMMED_BYTES);

    (void)hipMemsetAsync(summed, 0, WS_SUMMED_BYTES, stream);
    prep_weights<<<736, 64, 0, stream>>>(mW1, mW2, mW3, uW1, uW2, uW3, wf);
    msg_kernel<true><<<NEDGES / 64, 256, msg_lds, stream>>>(
        ns, nullptr, edg, verts, wf, mb1, mb2, mb3, summed, nullptr);
    upd_kernel<false><<<NNODES / 32, 128, upd_lds, stream>>>(
        ns, summed, nullptr, nullptr, nullptr, wf, ub1, ub2, ub3, out);
  }
}